// Round 4
// baseline (392.845 us; speedup 1.0000x reference)
//
#include <hip/hip_runtime.h>
#include <math.h>

// ============================================================================
// R16: R15 base (378.8us) + scores_k occupancy & L2-locality rebuild.
// R15 lesson: async pipeline changed NOTHING on scores_k (84us, MfmaUtil 26,
// Occ 16%) -> not a staging-latency problem. Two structural issues instead:
// (a) 80KB LDS capped occupancy at ~1.3 blocks/CU; barriers lockstep waves.
// (b) FETCH 152MB vs 42MB unique data: blocks sharing a Q-tile round-robin
//     across 8 XCDs -> Q re-fetched into every XCD L2 (~1.8TB/s L3 path).
// Fix: (1) Q direct global->register (each wave only reads its OWN 16 rows;
// LDS round trip was pure overhead). LDS 80KB->16KB (K dbuf only);
// __launch_bounds__(256,4) targets <=128 VGPR -> 4 blocks/CU.
// (2) XCD-chunked tri swizzle (528%8==0, bijective): same-Q-tile blocks land
// on one XCD -> Q-tile fetched once per XCD, not 8x.
// vmcnt(2) per iter retires all older loads (in-order retirement covers all
// waves' K before the barrier); Q register deps are compiler-tracked.
// Predicted: scores Occ 16->~40%, FETCH -50%, dur 84->~35-45us, total ~335.
// Numerics identical (absmax 0.015625 expected).
// ============================================================================

#define B_ 2
#define T_ 2048
#define C_ 512
#define NB_ 4
#define C2_ 1024  // hi|lo row width for Qcat/Kcat

typedef unsigned short u16;
typedef unsigned char u8;
using short8 = __attribute__((ext_vector_type(8))) short;
using bf16x8 = __attribute__((ext_vector_type(8))) __bf16;
using f32x4  = __attribute__((ext_vector_type(4))) float;

__device__ __forceinline__ float bf2f(u16 u) {
  union { unsigned int i; float f; } v; v.i = ((unsigned int)u) << 16; return v.f;
}
__device__ __forceinline__ u16 f2bf(float f) {  // round-to-nearest-even
  union { float f; unsigned int i; } v; v.f = f;
  unsigned int u = v.i;
  return (u16)((u + 0x7fffu + ((u >> 16) & 1u)) >> 16);
}
__device__ __forceinline__ f32x4 mfma16x16x32(short8 a, short8 b, f32x4 c) {
  return __builtin_amdgcn_mfma_f32_16x16x32_bf16(
      __builtin_bit_cast(bf16x8, a), __builtin_bit_cast(bf16x8, b), c, 0, 0, 0);
}
__device__ __forceinline__ void split8(const float* s, uint4& hi, uint4& lo) {
  u16 h[8], l[8];
#pragma unroll
  for (int j = 0; j < 8; ++j) {
    h[j] = f2bf(s[j]);
    l[j] = f2bf(s[j] - bf2f(h[j]));
  }
  hi.x = h[0] | ((unsigned)h[1] << 16); hi.y = h[2] | ((unsigned)h[3] << 16);
  hi.z = h[4] | ((unsigned)h[5] << 16); hi.w = h[6] | ((unsigned)h[7] << 16);
  lo.x = l[0] | ((unsigned)l[1] << 16); lo.y = l[2] | ((unsigned)l[3] << 16);
  lo.z = l[4] | ((unsigned)l[5] << 16); lo.w = l[6] | ((unsigned)l[7] << 16);
}
// LDS bank swizzle (kept for gemm_qk/gemm_hi/pv_k).
__device__ __forceinline__ int swz(int row) { return ((row >> 1) & 3) << 3; }

// ---------------------------------------------------------------------------
// Split-precision 64x64 GEMM with fused RoPE epilogue (R8 version).
// MODE 1: +1/sqrt(C) scale -> Qcat (B,NB,T,[hi512|lo512]).
// MODE 2: -> Kcat (B*T,[hi512|lo512]).
// ---------------------------------------------------------------------------
template <int MODE>
__global__ __launch_bounds__(256) void gemm_qk(const float* __restrict__ A,
                                               const float* __restrict__ W,
                                               u16* __restrict__ out,
                                               const float* __restrict__ cosT,
                                               const float* __restrict__ sinT,
                                               const int N, const int K) {
  __shared__ u16 Ah[64][32], Al[64][32];
  __shared__ u16 Bh[64][32], Bl[64][32];  // [n][k]
  const int tid = threadIdx.x;
  const int wave = tid >> 6, lane = tid & 63;
  const int m0 = blockIdx.y << 6, n0 = blockIdx.x << 6;
  const f32x4 zero = {0.f, 0.f, 0.f, 0.f};
  f32x4 acc[4] = {zero, zero, zero, zero};
  const int srow = tid >> 2, koff = ((tid & 3) << 3) ^ swz(tid >> 2);
  const int lrow = lane & 15, lk = ((lane >> 4) << 3) ^ swz(lane & 15);
  for (int kk = 0; kk < K; kk += 32) {
    const int kg = (tid & 3) << 3;  // global k sub-offset (unswizzled)
    float av[8];
    *(float4*)(av) = *(const float4*)(&A[(size_t)(m0 + srow) * K + kk + kg]);
    *(float4*)(av + 4) =
        *(const float4*)(&A[(size_t)(m0 + srow) * K + kk + kg + 4]);
    uint4 hi, lo;
    split8(av, hi, lo);
    *(uint4*)(&Ah[srow][koff]) = hi;
    *(uint4*)(&Al[srow][koff]) = lo;
    float wv[8];
#pragma unroll
    for (int j = 0; j < 8; ++j)
      wv[j] = W[(size_t)(kk + kg + j) * N + n0 + srow];
    split8(wv, hi, lo);
    *(uint4*)(&Bh[srow][koff]) = hi;
    *(uint4*)(&Bl[srow][koff]) = lo;
    __syncthreads();
    short8 ah = *(const short8*)(&Ah[(wave << 4) + lrow][lk]);
    short8 al = *(const short8*)(&Al[(wave << 4) + lrow][lk]);
#pragma unroll
    for (int ns = 0; ns < 4; ++ns) {
      short8 bh = *(const short8*)(&Bh[(ns << 4) + lrow][lk]);
      short8 bl = *(const short8*)(&Bl[(ns << 4) + lrow][lk]);
      acc[ns] = mfma16x16x32(ah, bh, acc[ns]);
      acc[ns] = mfma16x16x32(al, bh, acc[ns]);
      acc[ns] = mfma16x16x32(ah, bl, acc[ns]);
    }
    __syncthreads();
  }
  const int r0 = m0 + (wave << 4) + ((lane >> 4) << 2);
  const int cb = n0 + (lane & 15);
#pragma unroll
  for (int ns = 0; ns < 4; ++ns) {
#pragma unroll
    for (int r = 0; r < 4; ++r) {
      const int rg = r0 + r;
      const int cg = cb + (ns << 4);
      float v = acc[ns][r];
      float pv = __shfl_xor(v, 1);  // partner column of the RoPE pair
      const int t = rg & (T_ - 1);
      const int c = (MODE == 1) ? (cg & (C_ - 1)) : cg;
      const int i = c >> 1;
      const float cf = cosT[(t << 8) + i];
      const float sf = sinT[(t << 8) + i];
      float x1 = (lane & 1) ? pv : v;
      float x2 = (lane & 1) ? v : pv;
      float y = (lane & 1) ? (x1 * sf + x2 * cf) : (x1 * cf - x2 * sf);
      if (MODE == 1) y *= 0.044194173824159216f;  // 1/sqrt(512)
      const u16 hi = f2bf(y);
      const u16 lo = f2bf(y - bf2f(hi));
      size_t rowoff;
      if (MODE == 1) {
        const int b = rg >> 11, n = cg >> 9;
        rowoff = ((size_t)((b * NB_ + n) * T_ + t)) * C2_;
      } else {
        rowoff = (size_t)rg * C2_;
      }
      out[rowoff + c] = hi;
      out[rowoff + C_ + c] = lo;
    }
  }
}

// ---------------------------------------------------------------------------
// Plain hi-only GEMM: A f32 (AF32=1) or bf16, W f32; out bf16 or f32 (OF32).
// ---------------------------------------------------------------------------
template <int AF32, int OF32>
__global__ __launch_bounds__(256) void gemm_hi(const void* __restrict__ Ap,
                                               const float* __restrict__ W,
                                               void* __restrict__ outp,
                                               const int N, const int K) {
  __shared__ u16 As[64][32];
  __shared__ u16 Bs[64][32];
  const int tid = threadIdx.x;
  const int wave = tid >> 6, lane = tid & 63;
  const int m0 = blockIdx.y << 6, n0 = blockIdx.x << 6;
  const f32x4 zero = {0.f, 0.f, 0.f, 0.f};
  f32x4 acc[4] = {zero, zero, zero, zero};
  const int srow = tid >> 2, koff = ((tid & 3) << 3) ^ swz(tid >> 2);
  const int lrow = lane & 15, lk = ((lane >> 4) << 3) ^ swz(lane & 15);
  for (int kk = 0; kk < K; kk += 32) {
    const int kg = (tid & 3) << 3;
    if (AF32) {
      const float* A = (const float*)Ap;
      float av[8];
      *(float4*)(av) = *(const float4*)(&A[(size_t)(m0 + srow) * K + kk + kg]);
      *(float4*)(av + 4) =
          *(const float4*)(&A[(size_t)(m0 + srow) * K + kk + kg + 4]);
      uint4 hi;
      hi.x = f2bf(av[0]) | ((unsigned)f2bf(av[1]) << 16);
      hi.y = f2bf(av[2]) | ((unsigned)f2bf(av[3]) << 16);
      hi.z = f2bf(av[4]) | ((unsigned)f2bf(av[5]) << 16);
      hi.w = f2bf(av[6]) | ((unsigned)f2bf(av[7]) << 16);
      *(uint4*)(&As[srow][koff]) = hi;
    } else {
      const u16* A = (const u16*)Ap;
      *(uint4*)(&As[srow][koff]) =
          *(const uint4*)(&A[(size_t)(m0 + srow) * K + kk + kg]);
    }
    uint4 hi;
    {
      float w[8];
#pragma unroll
      for (int j = 0; j < 8; ++j)
        w[j] = W[(size_t)(kk + kg + j) * N + n0 + srow];
      hi.x = f2bf(w[0]) | ((unsigned)f2bf(w[1]) << 16);
      hi.y = f2bf(w[2]) | ((unsigned)f2bf(w[3]) << 16);
      hi.z = f2bf(w[4]) | ((unsigned)f2bf(w[5]) << 16);
      hi.w = f2bf(w[6]) | ((unsigned)f2bf(w[7]) << 16);
    }
    *(uint4*)(&Bs[srow][koff]) = hi;
    __syncthreads();
    short8 af = *(const short8*)(&As[(wave << 4) + lrow][lk]);
#pragma unroll
    for (int ns = 0; ns < 4; ++ns) {
      short8 bf = *(const short8*)(&Bs[(ns << 4) + lrow][lk]);
      acc[ns] = mfma16x16x32(af, bf, acc[ns]);
    }
    __syncthreads();
  }
  const int r0 = m0 + (wave << 4) + ((lane >> 4) << 2);
  const int cb = n0 + (lane & 15);
#pragma unroll
  for (int ns = 0; ns < 4; ++ns) {
#pragma unroll
    for (int r = 0; r < 4; ++r) {
      const size_t idx = (size_t)(r0 + r) * N + cb + (ns << 4);
      if (OF32) ((float*)outp)[idx] = acc[ns][r];
      else ((u16*)outp)[idx] = f2bf(acc[ns][r]);
    }
  }
}

// ---------------------------------------------------------------------------
// Vraw (B,T,NB*C) bf16 -> VT (B,NB,C,T) tiled transpose, 64x64 tiles.
// ---------------------------------------------------------------------------
__global__ __launch_bounds__(256) void transpose_v_k(const u16* __restrict__ Vraw,
                                                     u16* __restrict__ VT) {
  const int bid = blockIdx.x;
  const int ct = bid & 7;
  const int ttile = (bid >> 3) & 31;
  const int n = (bid >> 8) & 3;
  const int b = bid >> 10;
  __shared__ u16 tile[64][68];
  const int tid = threadIdx.x;
  const int rr = tid >> 4;
  const int cc = (tid & 15) << 2;
  const int t0 = ttile << 6, c0 = ct << 6;
#pragma unroll
  for (int it = 0; it < 4; ++it) {
    const int r = (it << 4) + rr;
    *(ushort4*)(&tile[r][cc]) = *(const ushort4*)(
        &Vraw[((size_t)((b << 11) + t0 + r)) * (NB_ * C_) + n * C_ + c0 + cc]);
  }
  __syncthreads();
#pragma unroll
  for (int it = 0; it < 4; ++it) {
    const int c = (it << 4) + rr;
    ushort4 w;
    w.x = tile[cc + 0][c]; w.y = tile[cc + 1][c];
    w.z = tile[cc + 2][c]; w.w = tile[cc + 3][c];
    *(ushort4*)(&VT[((size_t)((b * NB_ + n) * C_ + c0 + c)) * T_ + t0 + cc]) = w;
  }
}

// ---------------------------------------------------------------------------
// Scores (R16): per lower-tri 64x64 (t,s) tile, 4 branches, split-precision.
// Q direct global->register (each wave only consumes its own 16 rows; no LDS
// round trip). K-only double-buffered LDS (16KB) via global_load_lds, raw
// s_barrier + vmcnt(2). XCD-chunked tri swizzle (528%8==0, bijective) so
// same-Q-tile blocks share one XCD L2.
// ---------------------------------------------------------------------------
__global__ __launch_bounds__(256, 4) void scores_k(const u16* __restrict__ Qcat,
                                                   const u16* __restrict__ Kcat,
                                                   u16* __restrict__ Mout,
                                                   u8* __restrict__ Mask) {
  // XCD-chunked swizzle: 8 XCDs x 66 consecutive tris each.
  const int tri = ((blockIdx.x & 7) * 66) + (blockIdx.x >> 3);
  int tt = (int)((sqrtf(8.f * (float)tri + 1.f) - 1.f) * 0.5f);
  while ((tt + 1) * (tt + 2) / 2 <= tri) ++tt;
  while (tt * (tt + 1) / 2 > tri) --tt;
  const int ss = tri - tt * (tt + 1) / 2;
  const int b = blockIdx.y;
  __shared__ __align__(16) u16 Kh[2][64][32], Kl[2][64][32];
  const int tid = threadIdx.x;
  const int wave = tid >> 6, lane = tid & 63;
  const int t0 = tt << 6, s0 = ss << 6;
  const f32x4 zero = {0.f, 0.f, 0.f, 0.f};
  f32x4 acc[NB_][4];
  for (int n = 0; n < NB_; ++n)
    for (int j = 0; j < 4; ++j) acc[n][j] = zero;
  const int srow = tid >> 2, kg = (tid & 3) << 3;
  const int lrow = lane & 15, lk = (lane >> 4) << 3;
  const int wrow = wave << 4;
  const size_t qstride = (size_t)T_ * C2_;
  // per-lane Q base: row t0+wrow+lrow (own rows only), col-group lk.
  const size_t qb0 =
      ((size_t)(b * NB_ * T_ + t0 + wrow + lrow)) * C2_ + lk;
  const size_t kbase = ((size_t)((b << 11) + s0 + srow)) * C2_ + kg;

  // Stage one 32-wide K-chunk into buffer d: per wave 2 gload_lds_dwordx4;
  // lane l lands at Kh/Kl[d][wrow + (l>>2)][(l&3)*8] (linear).
  auto stage_k = [&](int d, int kko) {
    __builtin_amdgcn_global_load_lds(
        (const __attribute__((address_space(1))) void*)&Kcat[kbase + kko],
        (__attribute__((address_space(3))) void*)&Kh[d][wrow][0], 16, 0, 0);
    __builtin_amdgcn_global_load_lds(
        (const __attribute__((address_space(1))) void*)&Kcat[kbase + kko + C_],
        (__attribute__((address_space(3))) void*)&Kl[d][wrow][0], 16, 0, 0);
  };

  stage_k(0, 0);
  int cur = 0;
  for (int kk = 0; kk < C_; kk += 32) {
    if (kk + 32 < C_) stage_k(cur ^ 1, kk + 32);
    // Q fragments for THIS chunk, straight to registers (compiler-tracked).
    short8 qh[NB_], ql[NB_];
#pragma unroll
    for (int n = 0; n < NB_; ++n) {
      const size_t qb = qb0 + (size_t)n * qstride + kk;
      qh[n] = *(const short8*)(&Qcat[qb]);
      ql[n] = *(const short8*)(&Qcat[qb + C_]);
    }
    if (kk + 32 < C_) {
      // retire everything older than the 2 next-chunk K stages
      asm volatile("s_waitcnt vmcnt(2)" ::: "memory");
    } else {
      asm volatile("s_waitcnt vmcnt(0)" ::: "memory");
    }
    __builtin_amdgcn_sched_barrier(0);
    __builtin_amdgcn_s_barrier();  // raw: no implicit vmcnt drain
    __builtin_amdgcn_sched_barrier(0);
#pragma unroll
    for (int ns = 0; ns < 4; ++ns) {
      short8 kh = *(const short8*)(&Kh[cur][(ns << 4) + lrow][lk]);
      short8 kl = *(const short8*)(&Kl[cur][(ns << 4) + lrow][lk]);
#pragma unroll
      for (int n = 0; n < NB_; ++n) {
        acc[n][ns] = mfma16x16x32(qh[n], kh, acc[n][ns]);
        acc[n][ns] = mfma16x16x32(ql[n], kh, acc[n][ns]);
        acc[n][ns] = mfma16x16x32(qh[n], kl, acc[n][ns]);
      }
    }
    __builtin_amdgcn_sched_barrier(0);
    asm volatile("" ::: "memory");
    __builtin_amdgcn_s_barrier();  // all reads of buf[cur] done before re-stage
    __builtin_amdgcn_sched_barrier(0);
    cur ^= 1;
  }
  const int tb = t0 + (wave << 4) + ((lane >> 4) << 2);
  const int sb = s0 + (lane & 15);
#pragma unroll
  for (int ns = 0; ns < 4; ++ns) {
#pragma unroll
    for (int r = 0; r < 4; ++r) {
      const int t = tb + r, s = sb + (ns << 4);
      float a0 = acc[0][ns][r], a1 = acc[1][ns][r];
      float a2 = acc[2][ns][r], a3 = acc[3][ns][r];
      float m = fmaxf(fmaxf(a0, a1), fmaxf(a2, a3));
      u8 msk = (u8)((a0 == m) | ((a1 == m) << 1) | ((a2 == m) << 2) |
                    ((a3 == m) << 3));
      if (s > t) { m = -__builtin_inff(); msk = 0; }
      const size_t idx = (size_t)b * T_ * T_ + (size_t)t * T_ + s;
      Mout[idx] = f2bf(m);
      Mask[idx] = msk;
    }
  }
}

// ---------------------------------------------------------------------------
// Per-row softmax stats from bf16 M: rowmax, 1/sum(exp). One wave per (b,t).
// ---------------------------------------------------------------------------
__global__ __launch_bounds__(256) void rowstats_k(const u16* __restrict__ Mb,
                                                  float* __restrict__ Rm,
                                                  float* __restrict__ Rz) {
  const int r = (blockIdx.x << 2) + (threadIdx.x >> 6);
  const int lane = threadIdx.x & 63;
  const int b = r >> 11, t = r & (T_ - 1);
  const u16* row = Mb + (size_t)b * T_ * T_ + (size_t)t * T_;
  float m = -__builtin_inff();
  for (int s = lane; s <= t; s += 64) m = fmaxf(m, bf2f(row[s]));
#pragma unroll
  for (int off = 32; off; off >>= 1) m = fmaxf(m, __shfl_xor(m, off));
  float z = 0.f;
  for (int s = lane; s <= t; s += 64) z += expf(bf2f(row[s]) - m);
#pragma unroll
  for (int off = 32; off; off >>= 1) z += __shfl_xor(z, off);
  if (lane == 0) { Rm[r] = m; Rz[r] = 1.f / z; }
}

// ---------------------------------------------------------------------------
// P-build: P[b,t,s] = f2bf(exp(M - rm) * rz). One block per (b,t) row.
// ---------------------------------------------------------------------------
__global__ __launch_bounds__(256) void pbuild_k(const u16* __restrict__ Mb,
                                                const float* __restrict__ Rm,
                                                const float* __restrict__ Rz,
                                                u16* __restrict__ Pb) {
  const int r = blockIdx.x;
  const float rm = Rm[r], rz = Rz[r];
  const size_t off = ((size_t)r << 11) + (threadIdx.x << 3);
  ushort4 m0 = *(const ushort4*)(&Mb[off]);
  ushort4 m1 = *(const ushort4*)(&Mb[off + 4]);
  u16 o[8];
  o[0] = f2bf(expf(bf2f(m0.x) - rm) * rz);
  o[1] = f2bf(expf(bf2f(m0.y) - rm) * rz);
  o[2] = f2bf(expf(bf2f(m0.z) - rm) * rz);
  o[3] = f2bf(expf(bf2f(m0.w) - rm) * rz);
  o[4] = f2bf(expf(bf2f(m1.x) - rm) * rz);
  o[5] = f2bf(expf(bf2f(m1.y) - rm) * rz);
  o[6] = f2bf(expf(bf2f(m1.z) - rm) * rz);
  o[7] = f2bf(expf(bf2f(m1.w) - rm) * rz);
  uint4 w;
  w.x = o[0] | ((unsigned)o[1] << 16); w.y = o[2] | ((unsigned)o[3] << 16);
  w.z = o[4] | ((unsigned)o[5] << 16); w.w = o[6] | ((unsigned)o[7] << 16);
  *(uint4*)(&Pb[off]) = w;
}

// ---------------------------------------------------------------------------
// Routed PV, paired tiles + c-split (R13): grid (16,16,2); block y handles
// t-tiles y AND 31-y (66 chunks, perfect balance); blockIdx.y picks a 32-wide
// c stripe. 2 blocks/CU. LDS 24KB. One-chunk register prefetch kept.
// R14: swizzled Ps/Vs staging + reads.
// ---------------------------------------------------------------------------
__global__ __launch_bounds__(256) void pv_k(const u16* __restrict__ Pb,
                                            const u8* __restrict__ Mask,
                                            const u16* __restrict__ VT,
                                            u16* __restrict__ Y) {
  const int ypair = blockIdx.x, cblk = blockIdx.y, b = blockIdx.z;
  const int c0 = cblk << 5;  // 32-wide c stripe
  __shared__ u16 Ps[NB_][64][32];
  __shared__ u16 Vs[NB_][32][32];
  const int tid = threadIdx.x;
  const int wave = tid >> 6, lane = tid & 63;
  const int prow = tid >> 2, soff = (tid & 3) << 3;   // global P sub-offset
  const int psoff = soff ^ swz(prow);                  // swizzled LDS col
  const int vrow = tid >> 3, vsoff = (tid & 7) << 2;  // global V sub-offset
  const int vcol = ((((tid & 7) >> 1) ^ ((vrow >> 1) & 3)) << 3) |
                   ((tid & 1) << 2);                   // swizzled LDS col
  const int lrow = lane & 15, lk = ((lane >> 4) << 3) ^ swz(lane & 15);
  const f32x4 zero = {0.f, 0.f, 0.f, 0.f};
  const size_t vrow_base[NB_] = {
      ((size_t)((b * NB_ + 0) * C_ + c0 + vrow)) * T_,
      ((size_t)((b * NB_ + 1) * C_ + c0 + vrow)) * T_,
      ((size_t)((b * NB_ + 2) * C_ + c0 + vrow)) * T_,
      ((size_t)((b * NB_ + 3) * C_ + c0 + vrow)) * T_};

  for (int half = 0; half < 2; ++half) {
    const int tt = half ? (31 - ypair) : ypair;
    const int t0 = tt << 6;
    const int nchunk = (tt + 1) << 1;
    const size_t pro = ((size_t)((b << 11) + t0 + prow)) << 11;
    f32x4 acc[2] = {zero, zero};
    uint4 pu; uint2 mk2; uint2 vv[NB_];
    // prefetch chunk 0
    pu = *(const uint4*)(&Pb[pro + soff]);
    mk2 = *(const uint2*)(&Mask[pro + soff]);
#pragma unroll
    for (int n = 0; n < NB_; ++n)
      vv[n] = *(const uint2*)(&VT[vrow_base[n] + vsoff]);
    for (int ck = 0; ck < nchunk; ++ck) {
      u16 p[8] = {(u16)pu.x, (u16)(pu.x >> 16), (u16)pu.y, (u16)(pu.y >> 16),
                  (u16)pu.z, (u16)(pu.z >> 16), (u16)pu.w, (u16)(pu.w >> 16)};
      u8 mk[8] = {(u8)mk2.x, (u8)(mk2.x >> 8), (u8)(mk2.x >> 16),
                  (u8)(mk2.x >> 24), (u8)mk2.y, (u8)(mk2.y >> 8),
                  (u8)(mk2.y >> 16), (u8)(mk2.y >> 24)};
#pragma unroll
      for (int n = 0; n < NB_; ++n) {
        uint4 wv;
        wv.x = (unsigned)(((mk[0] >> n) & 1) ? p[0] : 0) |
               ((unsigned)(((mk[1] >> n) & 1) ? p[1] : 0) << 16);
        wv.y = (unsigned)(((mk[2] >> n) & 1) ? p[2] : 0) |
               ((unsigned)(((mk[3] >> n) & 1) ? p[3] : 0) << 16);
        wv.z = (unsigned)(((mk[4] >> n) & 1) ? p[4] : 0) |
               ((unsigned)(((mk[5] >> n) & 1) ? p[5] : 0) << 16);
        wv.w = (unsigned)(((mk[6] >> n) & 1) ? p[6] : 0) |
               ((unsigned)(((mk[7] >> n) & 1) ? p[7] : 0) << 16);
        *(uint4*)(&Ps[n][prow][psoff]) = wv;
        *(uint2*)(&Vs[n][vrow][vcol]) = vv[n];
      }
      __syncthreads();
      if (ck + 1 < nchunk) {  // prefetch next chunk (overlaps MFMA)
        const int sB = (ck + 1) << 5;
        pu = *(const uint4*)(&Pb[pro + sB + soff]);
        mk2 = *(const uint2*)(&Mask[pro + sB + soff]);
#pragma unroll
        for (int n = 0; n < NB_; ++n)
          vv[n] = *(const uint2*)(&VT[vrow_base[n] + sB + vsoff]);
      }
#pragma unroll
      for (int n = 0; n < NB_; ++n) {
        short8 af = *(const short8*)(&Ps[n][(wave << 4) + lrow][lk]);
#pragma unroll
        for (int cs = 0; cs < 2; ++cs) {
          short8 bf = *(const short8*)(&Vs[n][(cs << 4) + lrow][lk]);
          acc[cs] = mfma16x16x32(af, bf, acc[cs]);
        }
      }
      __syncthreads();
    }
    const int tb = t0 + (wave << 4) + ((lane >> 4) << 2);
    const int cbs = c0 + (lane & 15);
#pragma unroll
    for (int cs = 0; cs < 2; ++cs) {
#pragma unroll
      for (int r = 0; r < 4; ++r) {
        Y[(size_t)((b << 11) + tb + r) * C_ + cbs + (cs << 4)] =
            f2bf(acc[cs][r]);
      }
    }
  }
}

// ---------------------------------------------------------------------------
extern "C" void kernel_launch(void* const* d_in, const int* in_sizes, int n_in,
                              void* d_out, int out_size, void* d_ws,
                              size_t ws_size, hipStream_t stream) {
  (void)in_sizes; (void)n_in; (void)out_size; (void)ws_size;
  const float* a    = (const float*)d_in[0];
  const float* x    = (const float*)d_in[1];
  const float* Wq   = (const float*)d_in[2];
  const float* Wk   = (const float*)d_in[3];
  const float* Wv   = (const float*)d_in[4];
  const float* Wo   = (const float*)d_in[5];
  const float* cosT = (const float*)d_in[6];
  const float* sinT = (const float*)d_in[7];

  char* w = (char*)d_ws;
  u16* Qcat   = (u16*)(w + 0);           // 33.5MB -> first 4.2MB reused as Y
  u16* Kcat   = (u16*)(w + 33554432);    //  8.4MB
  u16* Vraw   = (u16*)(w + 41943040);    // 16.8MB -> reused as bf16 M
  u16* VT     = (u16*)(w + 58720256);    // 16.8MB
  u8*  Mask   = (u8*)(w + 75497472);     //  8.4MB
  float* Rm   = (float*)(w + 83886080);  //  16KB
  float* Rz   = (float*)(w + 83902464);  //  16KB
  u16* Pb     = (u16*)(w + 83918848);    // 16.8MB (end 100,696,064)
  u16* Mb     = Vraw;
  u16* Y      = Qcat;

  const dim3 blk(256);
  gemm_qk<1><<<dim3(32, 64), blk, 0, stream>>>(a, Wq, Qcat, cosT, sinT, 2048, 512);
  gemm_qk<2><<<dim3(8, 64), blk, 0, stream>>>(x, Wk, Kcat, cosT, sinT, 512, 512);
  gemm_hi<1, 0><<<dim3(32, 64), blk, 0, stream>>>(a, Wv, (void*)Vraw, 2048, 512);
  transpose_v_k<<<dim3(2048), blk, 0, stream>>>(Vraw, VT);
  scores_k<<<dim3(528, 2), blk, 0, stream>>>(Qcat, Kcat, Mb, Mask);
  rowstats_k<<<dim3(1024), blk, 0, stream>>>(Mb, Rm, Rz);
  pbuild_k<<<dim3(4096), blk, 0, stream>>>(Mb, Rm, Rz, Pb);
  pv_k<<<dim3(16, 16, 2), blk, 0, stream>>>(Pb, Mask, VT, Y);
  gemm_hi<0, 1><<<dim3(8, 64), blk, 0, stream>>>(Y, Wo, d_out, 512, 512);
}

// Round 5
// 392.513 us; speedup vs baseline: 1.0008x; 1.0008x over previous
//
#include <hip/hip_runtime.h>
#include <math.h>

// ============================================================================
// R17: R16 base (392.8us) + scores_k Q-register double-buffering.
// R16 post-mortem: FETCH 152->47MB (XCD swizzle + Q-direct GOOD) but dur
// 84->98us. Cause: Q reg loads issued after stage_k and consumed same-iter;
// in-order vmcnt retirement means the compiler's Q register-dep wait drains
// the next-chunk K stages too -> pipeline destroyed, full L2 latency exposed
// every iter. Fix: double-buffer Q REGISTERS (named A/B sets, x2-unrolled
// loop): issue {stage_k(next), loadQ(next->B)} then vmcnt(10), which retires
// exactly chunk-i's Q loads + K stage - both had the whole previous MFMA
// phase to complete. +32 VGPR (~150, launch_bounds(256,3) caps 170).
// s_setprio(1) around MFMA cluster (T5; phase-split schedule now exists).
// Predicted: scores 98 -> ~52-62us, MfmaUtil -> ~40%, total -> ~350us.
// Numerics identical (absmax 0.015625 expected).
// ============================================================================

#define B_ 2
#define T_ 2048
#define C_ 512
#define NB_ 4
#define C2_ 1024  // hi|lo row width for Qcat/Kcat

typedef unsigned short u16;
typedef unsigned char u8;
using short8 = __attribute__((ext_vector_type(8))) short;
using bf16x8 = __attribute__((ext_vector_type(8))) __bf16;
using f32x4  = __attribute__((ext_vector_type(4))) float;

__device__ __forceinline__ float bf2f(u16 u) {
  union { unsigned int i; float f; } v; v.i = ((unsigned int)u) << 16; return v.f;
}
__device__ __forceinline__ u16 f2bf(float f) {  // round-to-nearest-even
  union { float f; unsigned int i; } v; v.f = f;
  unsigned int u = v.i;
  return (u16)((u + 0x7fffu + ((u >> 16) & 1u)) >> 16);
}
__device__ __forceinline__ f32x4 mfma16x16x32(short8 a, short8 b, f32x4 c) {
  return __builtin_amdgcn_mfma_f32_16x16x32_bf16(
      __builtin_bit_cast(bf16x8, a), __builtin_bit_cast(bf16x8, b), c, 0, 0, 0);
}
__device__ __forceinline__ void split8(const float* s, uint4& hi, uint4& lo) {
  u16 h[8], l[8];
#pragma unroll
  for (int j = 0; j < 8; ++j) {
    h[j] = f2bf(s[j]);
    l[j] = f2bf(s[j] - bf2f(h[j]));
  }
  hi.x = h[0] | ((unsigned)h[1] << 16); hi.y = h[2] | ((unsigned)h[3] << 16);
  hi.z = h[4] | ((unsigned)h[5] << 16); hi.w = h[6] | ((unsigned)h[7] << 16);
  lo.x = l[0] | ((unsigned)l[1] << 16); lo.y = l[2] | ((unsigned)l[3] << 16);
  lo.z = l[4] | ((unsigned)l[5] << 16); lo.w = l[6] | ((unsigned)l[7] << 16);
}
// LDS bank swizzle (kept for gemm_qk/gemm_hi/pv_k).
__device__ __forceinline__ int swz(int row) { return ((row >> 1) & 3) << 3; }

// ---------------------------------------------------------------------------
// Split-precision 64x64 GEMM with fused RoPE epilogue (R8 version).
// MODE 1: +1/sqrt(C) scale -> Qcat (B,NB,T,[hi512|lo512]).
// MODE 2: -> Kcat (B*T,[hi512|lo512]).
// ---------------------------------------------------------------------------
template <int MODE>
__global__ __launch_bounds__(256) void gemm_qk(const float* __restrict__ A,
                                               const float* __restrict__ W,
                                               u16* __restrict__ out,
                                               const float* __restrict__ cosT,
                                               const float* __restrict__ sinT,
                                               const int N, const int K) {
  __shared__ u16 Ah[64][32], Al[64][32];
  __shared__ u16 Bh[64][32], Bl[64][32];  // [n][k]
  const int tid = threadIdx.x;
  const int wave = tid >> 6, lane = tid & 63;
  const int m0 = blockIdx.y << 6, n0 = blockIdx.x << 6;
  const f32x4 zero = {0.f, 0.f, 0.f, 0.f};
  f32x4 acc[4] = {zero, zero, zero, zero};
  const int srow = tid >> 2, koff = ((tid & 3) << 3) ^ swz(tid >> 2);
  const int lrow = lane & 15, lk = ((lane >> 4) << 3) ^ swz(lane & 15);
  for (int kk = 0; kk < K; kk += 32) {
    const int kg = (tid & 3) << 3;  // global k sub-offset (unswizzled)
    float av[8];
    *(float4*)(av) = *(const float4*)(&A[(size_t)(m0 + srow) * K + kk + kg]);
    *(float4*)(av + 4) =
        *(const float4*)(&A[(size_t)(m0 + srow) * K + kk + kg + 4]);
    uint4 hi, lo;
    split8(av, hi, lo);
    *(uint4*)(&Ah[srow][koff]) = hi;
    *(uint4*)(&Al[srow][koff]) = lo;
    float wv[8];
#pragma unroll
    for (int j = 0; j < 8; ++j)
      wv[j] = W[(size_t)(kk + kg + j) * N + n0 + srow];
    split8(wv, hi, lo);
    *(uint4*)(&Bh[srow][koff]) = hi;
    *(uint4*)(&Bl[srow][koff]) = lo;
    __syncthreads();
    short8 ah = *(const short8*)(&Ah[(wave << 4) + lrow][lk]);
    short8 al = *(const short8*)(&Al[(wave << 4) + lrow][lk]);
#pragma unroll
    for (int ns = 0; ns < 4; ++ns) {
      short8 bh = *(const short8*)(&Bh[(ns << 4) + lrow][lk]);
      short8 bl = *(const short8*)(&Bl[(ns << 4) + lrow][lk]);
      acc[ns] = mfma16x16x32(ah, bh, acc[ns]);
      acc[ns] = mfma16x16x32(al, bh, acc[ns]);
      acc[ns] = mfma16x16x32(ah, bl, acc[ns]);
    }
    __syncthreads();
  }
  const int r0 = m0 + (wave << 4) + ((lane >> 4) << 2);
  const int cb = n0 + (lane & 15);
#pragma unroll
  for (int ns = 0; ns < 4; ++ns) {
#pragma unroll
    for (int r = 0; r < 4; ++r) {
      const int rg = r0 + r;
      const int cg = cb + (ns << 4);
      float v = acc[ns][r];
      float pv = __shfl_xor(v, 1);  // partner column of the RoPE pair
      const int t = rg & (T_ - 1);
      const int c = (MODE == 1) ? (cg & (C_ - 1)) : cg;
      const int i = c >> 1;
      const float cf = cosT[(t << 8) + i];
      const float sf = sinT[(t << 8) + i];
      float x1 = (lane & 1) ? pv : v;
      float x2 = (lane & 1) ? v : pv;
      float y = (lane & 1) ? (x1 * sf + x2 * cf) : (x1 * cf - x2 * sf);
      if (MODE == 1) y *= 0.044194173824159216f;  // 1/sqrt(512)
      const u16 hi = f2bf(y);
      const u16 lo = f2bf(y - bf2f(hi));
      size_t rowoff;
      if (MODE == 1) {
        const int b = rg >> 11, n = cg >> 9;
        rowoff = ((size_t)((b * NB_ + n) * T_ + t)) * C2_;
      } else {
        rowoff = (size_t)rg * C2_;
      }
      out[rowoff + c] = hi;
      out[rowoff + C_ + c] = lo;
    }
  }
}

// ---------------------------------------------------------------------------
// Plain hi-only GEMM: A f32 (AF32=1) or bf16, W f32; out bf16 or f32 (OF32).
// ---------------------------------------------------------------------------
template <int AF32, int OF32>
__global__ __launch_bounds__(256) void gemm_hi(const void* __restrict__ Ap,
                                               const float* __restrict__ W,
                                               void* __restrict__ outp,
                                               const int N, const int K) {
  __shared__ u16 As[64][32];
  __shared__ u16 Bs[64][32];
  const int tid = threadIdx.x;
  const int wave = tid >> 6, lane = tid & 63;
  const int m0 = blockIdx.y << 6, n0 = blockIdx.x << 6;
  const f32x4 zero = {0.f, 0.f, 0.f, 0.f};
  f32x4 acc[4] = {zero, zero, zero, zero};
  const int srow = tid >> 2, koff = ((tid & 3) << 3) ^ swz(tid >> 2);
  const int lrow = lane & 15, lk = ((lane >> 4) << 3) ^ swz(lane & 15);
  for (int kk = 0; kk < K; kk += 32) {
    const int kg = (tid & 3) << 3;
    if (AF32) {
      const float* A = (const float*)Ap;
      float av[8];
      *(float4*)(av) = *(const float4*)(&A[(size_t)(m0 + srow) * K + kk + kg]);
      *(float4*)(av + 4) =
          *(const float4*)(&A[(size_t)(m0 + srow) * K + kk + kg + 4]);
      uint4 hi;
      hi.x = f2bf(av[0]) | ((unsigned)f2bf(av[1]) << 16);
      hi.y = f2bf(av[2]) | ((unsigned)f2bf(av[3]) << 16);
      hi.z = f2bf(av[4]) | ((unsigned)f2bf(av[5]) << 16);
      hi.w = f2bf(av[6]) | ((unsigned)f2bf(av[7]) << 16);
      *(uint4*)(&As[srow][koff]) = hi;
    } else {
      const u16* A = (const u16*)Ap;
      *(uint4*)(&As[srow][koff]) =
          *(const uint4*)(&A[(size_t)(m0 + srow) * K + kk + kg]);
    }
    uint4 hi;
    {
      float w[8];
#pragma unroll
      for (int j = 0; j < 8; ++j)
        w[j] = W[(size_t)(kk + kg + j) * N + n0 + srow];
      hi.x = f2bf(w[0]) | ((unsigned)f2bf(w[1]) << 16);
      hi.y = f2bf(w[2]) | ((unsigned)f2bf(w[3]) << 16);
      hi.z = f2bf(w[4]) | ((unsigned)f2bf(w[5]) << 16);
      hi.w = f2bf(w[6]) | ((unsigned)f2bf(w[7]) << 16);
    }
    *(uint4*)(&Bs[srow][koff]) = hi;
    __syncthreads();
    short8 af = *(const short8*)(&As[(wave << 4) + lrow][lk]);
#pragma unroll
    for (int ns = 0; ns < 4; ++ns) {
      short8 bf = *(const short8*)(&Bs[(ns << 4) + lrow][lk]);
      acc[ns] = mfma16x16x32(af, bf, acc[ns]);
    }
    __syncthreads();
  }
  const int r0 = m0 + (wave << 4) + ((lane >> 4) << 2);
  const int cb = n0 + (lane & 15);
#pragma unroll
  for (int ns = 0; ns < 4; ++ns) {
#pragma unroll
    for (int r = 0; r < 4; ++r) {
      const size_t idx = (size_t)(r0 + r) * N + cb + (ns << 4);
      if (OF32) ((float*)outp)[idx] = acc[ns][r];
      else ((u16*)outp)[idx] = f2bf(acc[ns][r]);
    }
  }
}

// ---------------------------------------------------------------------------
// Vraw (B,T,NB*C) bf16 -> VT (B,NB,C,T) tiled transpose, 64x64 tiles.
// ---------------------------------------------------------------------------
__global__ __launch_bounds__(256) void transpose_v_k(const u16* __restrict__ Vraw,
                                                     u16* __restrict__ VT) {
  const int bid = blockIdx.x;
  const int ct = bid & 7;
  const int ttile = (bid >> 3) & 31;
  const int n = (bid >> 8) & 3;
  const int b = bid >> 10;
  __shared__ u16 tile[64][68];
  const int tid = threadIdx.x;
  const int rr = tid >> 4;
  const int cc = (tid & 15) << 2;
  const int t0 = ttile << 6, c0 = ct << 6;
#pragma unroll
  for (int it = 0; it < 4; ++it) {
    const int r = (it << 4) + rr;
    *(ushort4*)(&tile[r][cc]) = *(const ushort4*)(
        &Vraw[((size_t)((b << 11) + t0 + r)) * (NB_ * C_) + n * C_ + c0 + cc]);
  }
  __syncthreads();
#pragma unroll
  for (int it = 0; it < 4; ++it) {
    const int c = (it << 4) + rr;
    ushort4 w;
    w.x = tile[cc + 0][c]; w.y = tile[cc + 1][c];
    w.z = tile[cc + 2][c]; w.w = tile[cc + 3][c];
    *(ushort4*)(&VT[((size_t)((b * NB_ + n) * C_ + c0 + c)) * T_ + t0 + cc]) = w;
  }
}

// ---------------------------------------------------------------------------
// Scores (R17): per lower-tri 64x64 (t,s) tile, 4 branches, split-precision.
// Q direct global->register, DOUBLE-BUFFERED (A/B named sets, x2-unrolled
// loop) so vmcnt(10) retires exactly the previous chunk's {Q loads + K
// stage}, all covered by a full MFMA phase. K dbuf LDS 16KB via
// global_load_lds. XCD-chunked tri swizzle. setprio around MFMA.
// ---------------------------------------------------------------------------
__global__ __launch_bounds__(256, 3) void scores_k(const u16* __restrict__ Qcat,
                                                   const u16* __restrict__ Kcat,
                                                   u16* __restrict__ Mout,
                                                   u8* __restrict__ Mask) {
  // XCD-chunked swizzle: 8 XCDs x 66 consecutive tris each.
  const int tri = ((blockIdx.x & 7) * 66) + (blockIdx.x >> 3);
  int tt = (int)((sqrtf(8.f * (float)tri + 1.f) - 1.f) * 0.5f);
  while ((tt + 1) * (tt + 2) / 2 <= tri) ++tt;
  while (tt * (tt + 1) / 2 > tri) --tt;
  const int ss = tri - tt * (tt + 1) / 2;
  const int b = blockIdx.y;
  __shared__ __align__(16) u16 Kh[2][64][32], Kl[2][64][32];
  const int tid = threadIdx.x;
  const int wave = tid >> 6, lane = tid & 63;
  const int t0 = tt << 6, s0 = ss << 6;
  const f32x4 zero = {0.f, 0.f, 0.f, 0.f};
  f32x4 acc[NB_][4];
  for (int n = 0; n < NB_; ++n)
    for (int j = 0; j < 4; ++j) acc[n][j] = zero;
  const int srow = tid >> 2, kg = (tid & 3) << 3;
  const int lrow = lane & 15, lk = (lane >> 4) << 3;
  const int wrow = wave << 4;
  const size_t qstride = (size_t)T_ * C2_;
  const size_t qb0 =
      ((size_t)(b * NB_ * T_ + t0 + wrow + lrow)) * C2_ + lk;
  const size_t kbase = ((size_t)((b << 11) + s0 + srow)) * C2_ + kg;

  auto stage_k = [&](int d, int kko) {
    __builtin_amdgcn_global_load_lds(
        (const __attribute__((address_space(1))) void*)&Kcat[kbase + kko],
        (__attribute__((address_space(3))) void*)&Kh[d][wrow][0], 16, 0, 0);
    __builtin_amdgcn_global_load_lds(
        (const __attribute__((address_space(1))) void*)&Kcat[kbase + kko + C_],
        (__attribute__((address_space(3))) void*)&Kl[d][wrow][0], 16, 0, 0);
  };
  auto loadQ = [&](int kko, short8* qh, short8* ql) {
#pragma unroll
    for (int n = 0; n < NB_; ++n) {
      const size_t qb = qb0 + (size_t)n * qstride + kko;
      qh[n] = *(const short8*)(&Qcat[qb]);
      ql[n] = *(const short8*)(&Qcat[qb + C_]);
    }
  };
  auto mma = [&](const short8* qh, const short8* ql, int d) {
    __builtin_amdgcn_s_setprio(1);
#pragma unroll
    for (int ns = 0; ns < 4; ++ns) {
      short8 kh = *(const short8*)(&Kh[d][(ns << 4) + lrow][lk]);
      short8 kl = *(const short8*)(&Kl[d][(ns << 4) + lrow][lk]);
#pragma unroll
      for (int n = 0; n < NB_; ++n) {
        acc[n][ns] = mfma16x16x32(qh[n], kh, acc[n][ns]);
        acc[n][ns] = mfma16x16x32(ql[n], kh, acc[n][ns]);
        acc[n][ns] = mfma16x16x32(qh[n], kl, acc[n][ns]);
      }
    }
    __builtin_amdgcn_s_setprio(0);
  };

  short8 qhA[NB_], qlA[NB_], qhB[NB_], qlB[NB_];
  // prologue: chunk 0 -> A regs + buf0
  loadQ(0, qhA, qlA);
  stage_k(0, 0);
  for (int k = 0; k < C_; k += 64) {
    // ---- half 1: compute chunk k (A regs, buf0); prefetch k+32 -> B/buf1
    stage_k(1, k + 32);
    loadQ(k + 32, qhB, qlB);
    asm volatile("s_waitcnt vmcnt(10)" ::: "memory");
    __builtin_amdgcn_sched_barrier(0);
    __builtin_amdgcn_s_barrier();  // raw: no implicit vmcnt drain
    __builtin_amdgcn_sched_barrier(0);
    mma(qhA, qlA, 0);
    __builtin_amdgcn_sched_barrier(0);
    asm volatile("" ::: "memory");
    __builtin_amdgcn_s_barrier();  // reads of buf0 done before its re-stage
    __builtin_amdgcn_sched_barrier(0);
    // ---- half 2: compute chunk k+32 (B regs, buf1); prefetch k+64 -> A/buf0
    if (k + 64 < C_) {
      stage_k(0, k + 64);
      loadQ(k + 64, qhA, qlA);
      asm volatile("s_waitcnt vmcnt(10)" ::: "memory");
    } else {
      asm volatile("s_waitcnt vmcnt(0)" ::: "memory");
    }
    __builtin_amdgcn_sched_barrier(0);
    __builtin_amdgcn_s_barrier();
    __builtin_amdgcn_sched_barrier(0);
    mma(qhB, qlB, 1);
    __builtin_amdgcn_sched_barrier(0);
    asm volatile("" ::: "memory");
    __builtin_amdgcn_s_barrier();
    __builtin_amdgcn_sched_barrier(0);
  }
  const int tb = t0 + (wave << 4) + ((lane >> 4) << 2);
  const int sb = s0 + (lane & 15);
#pragma unroll
  for (int ns = 0; ns < 4; ++ns) {
#pragma unroll
    for (int r = 0; r < 4; ++r) {
      const int t = tb + r, s = sb + (ns << 4);
      float a0 = acc[0][ns][r], a1 = acc[1][ns][r];
      float a2 = acc[2][ns][r], a3 = acc[3][ns][r];
      float m = fmaxf(fmaxf(a0, a1), fmaxf(a2, a3));
      u8 msk = (u8)((a0 == m) | ((a1 == m) << 1) | ((a2 == m) << 2) |
                    ((a3 == m) << 3));
      if (s > t) { m = -__builtin_inff(); msk = 0; }
      const size_t idx = (size_t)b * T_ * T_ + (size_t)t * T_ + s;
      Mout[idx] = f2bf(m);
      Mask[idx] = msk;
    }
  }
}

// ---------------------------------------------------------------------------
// Per-row softmax stats from bf16 M: rowmax, 1/sum(exp). One wave per (b,t).
// ---------------------------------------------------------------------------
__global__ __launch_bounds__(256) void rowstats_k(const u16* __restrict__ Mb,
                                                  float* __restrict__ Rm,
                                                  float* __restrict__ Rz) {
  const int r = (blockIdx.x << 2) + (threadIdx.x >> 6);
  const int lane = threadIdx.x & 63;
  const int b = r >> 11, t = r & (T_ - 1);
  const u16* row = Mb + (size_t)b * T_ * T_ + (size_t)t * T_;
  float m = -__builtin_inff();
  for (int s = lane; s <= t; s += 64) m = fmaxf(m, bf2f(row[s]));
#pragma unroll
  for (int off = 32; off; off >>= 1) m = fmaxf(m, __shfl_xor(m, off));
  float z = 0.f;
  for (int s = lane; s <= t; s += 64) z += expf(bf2f(row[s]) - m);
#pragma unroll
  for (int off = 32; off; off >>= 1) z += __shfl_xor(z, off);
  if (lane == 0) { Rm[r] = m; Rz[r] = 1.f / z; }
}

// ---------------------------------------------------------------------------
// P-build: P[b,t,s] = f2bf(exp(M - rm) * rz). One block per (b,t) row.
// ---------------------------------------------------------------------------
__global__ __launch_bounds__(256) void pbuild_k(const u16* __restrict__ Mb,
                                                const float* __restrict__ Rm,
                                                const float* __restrict__ Rz,
                                                u16* __restrict__ Pb) {
  const int r = blockIdx.x;
  const float rm = Rm[r], rz = Rz[r];
  const size_t off = ((size_t)r << 11) + (threadIdx.x << 3);
  ushort4 m0 = *(const ushort4*)(&Mb[off]);
  ushort4 m1 = *(const ushort4*)(&Mb[off + 4]);
  u16 o[8];
  o[0] = f2bf(expf(bf2f(m0.x) - rm) * rz);
  o[1] = f2bf(expf(bf2f(m0.y) - rm) * rz);
  o[2] = f2bf(expf(bf2f(m0.z) - rm) * rz);
  o[3] = f2bf(expf(bf2f(m0.w) - rm) * rz);
  o[4] = f2bf(expf(bf2f(m1.x) - rm) * rz);
  o[5] = f2bf(expf(bf2f(m1.y) - rm) * rz);
  o[6] = f2bf(expf(bf2f(m1.z) - rm) * rz);
  o[7] = f2bf(expf(bf2f(m1.w) - rm) * rz);
  uint4 w;
  w.x = o[0] | ((unsigned)o[1] << 16); w.y = o[2] | ((unsigned)o[3] << 16);
  w.z = o[4] | ((unsigned)o[5] << 16); w.w = o[6] | ((unsigned)o[7] << 16);
  *(uint4*)(&Pb[off]) = w;
}

// ---------------------------------------------------------------------------
// Routed PV, paired tiles + c-split (R13): grid (16,16,2); block y handles
// t-tiles y AND 31-y (66 chunks, perfect balance); blockIdx.y picks a 32-wide
// c stripe. 2 blocks/CU. LDS 24KB. One-chunk register prefetch kept.
// R14: swizzled Ps/Vs staging + reads.
// ---------------------------------------------------------------------------
__global__ __launch_bounds__(256) void pv_k(const u16* __restrict__ Pb,
                                            const u8* __restrict__ Mask,
                                            const u16* __restrict__ VT,
                                            u16* __restrict__ Y) {
  const int ypair = blockIdx.x, cblk = blockIdx.y, b = blockIdx.z;
  const int c0 = cblk << 5;  // 32-wide c stripe
  __shared__ u16 Ps[NB_][64][32];
  __shared__ u16 Vs[NB_][32][32];
  const int tid = threadIdx.x;
  const int wave = tid >> 6, lane = tid & 63;
  const int prow = tid >> 2, soff = (tid & 3) << 3;   // global P sub-offset
  const int psoff = soff ^ swz(prow);                  // swizzled LDS col
  const int vrow = tid >> 3, vsoff = (tid & 7) << 2;  // global V sub-offset
  const int vcol = ((((tid & 7) >> 1) ^ ((vrow >> 1) & 3)) << 3) |
                   ((tid & 1) << 2);                   // swizzled LDS col
  const int lrow = lane & 15, lk = ((lane >> 4) << 3) ^ swz(lane & 15);
  const f32x4 zero = {0.f, 0.f, 0.f, 0.f};
  const size_t vrow_base[NB_] = {
      ((size_t)((b * NB_ + 0) * C_ + c0 + vrow)) * T_,
      ((size_t)((b * NB_ + 1) * C_ + c0 + vrow)) * T_,
      ((size_t)((b * NB_ + 2) * C_ + c0 + vrow)) * T_,
      ((size_t)((b * NB_ + 3) * C_ + c0 + vrow)) * T_};

  for (int half = 0; half < 2; ++half) {
    const int tt = half ? (31 - ypair) : ypair;
    const int t0 = tt << 6;
    const int nchunk = (tt + 1) << 1;
    const size_t pro = ((size_t)((b << 11) + t0 + prow)) << 11;
    f32x4 acc[2] = {zero, zero};
    uint4 pu; uint2 mk2; uint2 vv[NB_];
    // prefetch chunk 0
    pu = *(const uint4*)(&Pb[pro + soff]);
    mk2 = *(const uint2*)(&Mask[pro + soff]);
#pragma unroll
    for (int n = 0; n < NB_; ++n)
      vv[n] = *(const uint2*)(&VT[vrow_base[n] + vsoff]);
    for (int ck = 0; ck < nchunk; ++ck) {
      u16 p[8] = {(u16)pu.x, (u16)(pu.x >> 16), (u16)pu.y, (u16)(pu.y >> 16),
                  (u16)pu.z, (u16)(pu.z >> 16), (u16)pu.w, (u16)(pu.w >> 16)};
      u8 mk[8] = {(u8)mk2.x, (u8)(mk2.x >> 8), (u8)(mk2.x >> 16),
                  (u8)(mk2.x >> 24), (u8)mk2.y, (u8)(mk2.y >> 8),
                  (u8)(mk2.y >> 16), (u8)(mk2.y >> 24)};
#pragma unroll
      for (int n = 0; n < NB_; ++n) {
        uint4 wv;
        wv.x = (unsigned)(((mk[0] >> n) & 1) ? p[0] : 0) |
               ((unsigned)(((mk[1] >> n) & 1) ? p[1] : 0) << 16);
        wv.y = (unsigned)(((mk[2] >> n) & 1) ? p[2] : 0) |
               ((unsigned)(((mk[3] >> n) & 1) ? p[3] : 0) << 16);
        wv.z = (unsigned)(((mk[4] >> n) & 1) ? p[4] : 0) |
               ((unsigned)(((mk[5] >> n) & 1) ? p[5] : 0) << 16);
        wv.w = (unsigned)(((mk[6] >> n) & 1) ? p[6] : 0) |
               ((unsigned)(((mk[7] >> n) & 1) ? p[7] : 0) << 16);
        *(uint4*)(&Ps[n][prow][psoff]) = wv;
        *(uint2*)(&Vs[n][vrow][vcol]) = vv[n];
      }
      __syncthreads();
      if (ck + 1 < nchunk) {  // prefetch next chunk (overlaps MFMA)
        const int sB = (ck + 1) << 5;
        pu = *(const uint4*)(&Pb[pro + sB + soff]);
        mk2 = *(const uint2*)(&Mask[pro + sB + soff]);
#pragma unroll
        for (int n = 0; n < NB_; ++n)
          vv[n] = *(const uint2*)(&VT[vrow_base[n] + sB + vsoff]);
      }
#pragma unroll
      for (int n = 0; n < NB_; ++n) {
        short8 af = *(const short8*)(&Ps[n][(wave << 4) + lrow][lk]);
#pragma unroll
        for (int cs = 0; cs < 2; ++cs) {
          short8 bf = *(const short8*)(&Vs[n][(cs << 4) + lrow][lk]);
          acc[cs] = mfma16x16x32(af, bf, acc[cs]);
        }
      }
      __syncthreads();
    }
    const int tb = t0 + (wave << 4) + ((lane >> 4) << 2);
    const int cbs = c0 + (lane & 15);
#pragma unroll
    for (int cs = 0; cs < 2; ++cs) {
#pragma unroll
      for (int r = 0; r < 4; ++r) {
        Y[(size_t)((b << 11) + tb + r) * C_ + cbs + (cs << 4)] =
            f2bf(acc[cs][r]);
      }
    }
  }
}

// ---------------------------------------------------------------------------
extern "C" void kernel_launch(void* const* d_in, const int* in_sizes, int n_in,
                              void* d_out, int out_size, void* d_ws,
                              size_t ws_size, hipStream_t stream) {
  (void)in_sizes; (void)n_in; (void)out_size; (void)ws_size;
  const float* a    = (const float*)d_in[0];
  const float* x    = (const float*)d_in[1];
  const float* Wq   = (const float*)d_in[2];
  const float* Wk   = (const float*)d_in[3];
  const float* Wv   = (const float*)d_in[4];
  const float* Wo   = (const float*)d_in[5];
  const float* cosT = (const float*)d_in[6];
  const float* sinT = (const float*)d_in[7];

  char* w = (char*)d_ws;
  u16* Qcat   = (u16*)(w + 0);           // 33.5MB -> first 4.2MB reused as Y
  u16* Kcat   = (u16*)(w + 33554432);    //  8.4MB
  u16* Vraw   = (u16*)(w + 41943040);    // 16.8MB -> reused as bf16 M
  u16* VT     = (u16*)(w + 58720256);    // 16.8MB
  u8*  Mask   = (u8*)(w + 75497472);     //  8.4MB
  float* Rm   = (float*)(w + 83886080);  //  16KB
  float* Rz   = (float*)(w + 83902464);  //  16KB
  u16* Pb     = (u16*)(w + 83918848);    // 16.8MB (end 100,696,064)
  u16* Mb     = Vraw;
  u16* Y      = Qcat;

  const dim3 blk(256);
  gemm_qk<1><<<dim3(32, 64), blk, 0, stream>>>(a, Wq, Qcat, cosT, sinT, 2048, 512);
  gemm_qk<2><<<dim3(8, 64), blk, 0, stream>>>(x, Wk, Kcat, cosT, sinT, 512, 512);
  gemm_hi<1, 0><<<dim3(32, 64), blk, 0, stream>>>(a, Wv, (void*)Vraw, 2048, 512);
  transpose_v_k<<<dim3(2048), blk, 0, stream>>>(Vraw, VT);
  scores_k<<<dim3(528, 2), blk, 0, stream>>>(Qcat, Kcat, Mb, Mask);
  rowstats_k<<<dim3(1024), blk, 0, stream>>>(Mb, Rm, Rz);
  pbuild_k<<<dim3(4096), blk, 0, stream>>>(Mb, Rm, Rz, Pb);
  pv_k<<<dim3(16, 16, 2), blk, 0, stream>>>(Pb, Mask, VT, Y);
  gemm_hi<0, 1><<<dim3(8, 64), blk, 0, stream>>>(Y, Wo, d_out, 512, 512);
}

// Round 6
// 384.438 us; speedup vs baseline: 1.0219x; 1.0210x over previous
//
#include <hip/hip_runtime.h>
#include <math.h>

// ============================================================================
// R18: scores_k reverted to proven R14 form (82.9us; R15/R16/R17 pipelining
// variants all 84-98us -> structure micro-opt is not the lever) + XCD tri
// chunking (R16 proved FETCH 210->47MB; scores blocks do uniform work so the
// remap is balance-neutral). NEW lever: pbuild_k FUSED into pv_k staging --
// P = f2bf(exp(M-rm)*rz) computed inline (rm/rz are per-row scalars, loaded
// once per half-tile; 8 expf/thread/chunk ~50cy vs ~500cy chunk). Deletes one
// dispatch + 34MB of M-read/P-write/P-read round trip. Bit-identical
// rounding (f2bf after exp, as pbuild did).
// Predicted: scores ~72-83us (FETCH -70%), pbuild gone (-~12us), pv +0-5us,
// total 392.5 -> ~362-372us. absmax 0.015625 expected.
// ============================================================================

#define B_ 2
#define T_ 2048
#define C_ 512
#define NB_ 4
#define C2_ 1024  // hi|lo row width for Qcat/Kcat

typedef unsigned short u16;
typedef unsigned char u8;
using short8 = __attribute__((ext_vector_type(8))) short;
using bf16x8 = __attribute__((ext_vector_type(8))) __bf16;
using f32x4  = __attribute__((ext_vector_type(4))) float;

__device__ __forceinline__ float bf2f(u16 u) {
  union { unsigned int i; float f; } v; v.i = ((unsigned int)u) << 16; return v.f;
}
__device__ __forceinline__ u16 f2bf(float f) {  // round-to-nearest-even
  union { float f; unsigned int i; } v; v.f = f;
  unsigned int u = v.i;
  return (u16)((u + 0x7fffu + ((u >> 16) & 1u)) >> 16);
}
__device__ __forceinline__ f32x4 mfma16x16x32(short8 a, short8 b, f32x4 c) {
  return __builtin_amdgcn_mfma_f32_16x16x32_bf16(
      __builtin_bit_cast(bf16x8, a), __builtin_bit_cast(bf16x8, b), c, 0, 0, 0);
}
__device__ __forceinline__ void split8(const float* s, uint4& hi, uint4& lo) {
  u16 h[8], l[8];
#pragma unroll
  for (int j = 0; j < 8; ++j) {
    h[j] = f2bf(s[j]);
    l[j] = f2bf(s[j] - bf2f(h[j]));
  }
  hi.x = h[0] | ((unsigned)h[1] << 16); hi.y = h[2] | ((unsigned)h[3] << 16);
  hi.z = h[4] | ((unsigned)h[5] << 16); hi.w = h[6] | ((unsigned)h[7] << 16);
  lo.x = l[0] | ((unsigned)l[1] << 16); lo.y = l[2] | ((unsigned)l[3] << 16);
  lo.z = l[4] | ((unsigned)l[5] << 16); lo.w = l[6] | ((unsigned)l[7] << 16);
}
// LDS bank swizzle: XOR the 16B column-group with row bits [2:1].
__device__ __forceinline__ int swz(int row) { return ((row >> 1) & 3) << 3; }

// ---------------------------------------------------------------------------
// Split-precision 64x64 GEMM with fused RoPE epilogue (R8 version).
// MODE 1: +1/sqrt(C) scale -> Qcat (B,NB,T,[hi512|lo512]).
// MODE 2: -> Kcat (B*T,[hi512|lo512]).
// ---------------------------------------------------------------------------
template <int MODE>
__global__ __launch_bounds__(256) void gemm_qk(const float* __restrict__ A,
                                               const float* __restrict__ W,
                                               u16* __restrict__ out,
                                               const float* __restrict__ cosT,
                                               const float* __restrict__ sinT,
                                               const int N, const int K) {
  __shared__ u16 Ah[64][32], Al[64][32];
  __shared__ u16 Bh[64][32], Bl[64][32];  // [n][k]
  const int tid = threadIdx.x;
  const int wave = tid >> 6, lane = tid & 63;
  const int m0 = blockIdx.y << 6, n0 = blockIdx.x << 6;
  const f32x4 zero = {0.f, 0.f, 0.f, 0.f};
  f32x4 acc[4] = {zero, zero, zero, zero};
  const int srow = tid >> 2, koff = ((tid & 3) << 3) ^ swz(tid >> 2);
  const int lrow = lane & 15, lk = ((lane >> 4) << 3) ^ swz(lane & 15);
  for (int kk = 0; kk < K; kk += 32) {
    const int kg = (tid & 3) << 3;  // global k sub-offset (unswizzled)
    float av[8];
    *(float4*)(av) = *(const float4*)(&A[(size_t)(m0 + srow) * K + kk + kg]);
    *(float4*)(av + 4) =
        *(const float4*)(&A[(size_t)(m0 + srow) * K + kk + kg + 4]);
    uint4 hi, lo;
    split8(av, hi, lo);
    *(uint4*)(&Ah[srow][koff]) = hi;
    *(uint4*)(&Al[srow][koff]) = lo;
    float wv[8];
#pragma unroll
    for (int j = 0; j < 8; ++j)
      wv[j] = W[(size_t)(kk + kg + j) * N + n0 + srow];
    split8(wv, hi, lo);
    *(uint4*)(&Bh[srow][koff]) = hi;
    *(uint4*)(&Bl[srow][koff]) = lo;
    __syncthreads();
    short8 ah = *(const short8*)(&Ah[(wave << 4) + lrow][lk]);
    short8 al = *(const short8*)(&Al[(wave << 4) + lrow][lk]);
#pragma unroll
    for (int ns = 0; ns < 4; ++ns) {
      short8 bh = *(const short8*)(&Bh[(ns << 4) + lrow][lk]);
      short8 bl = *(const short8*)(&Bl[(ns << 4) + lrow][lk]);
      acc[ns] = mfma16x16x32(ah, bh, acc[ns]);
      acc[ns] = mfma16x16x32(al, bh, acc[ns]);
      acc[ns] = mfma16x16x32(ah, bl, acc[ns]);
    }
    __syncthreads();
  }
  const int r0 = m0 + (wave << 4) + ((lane >> 4) << 2);
  const int cb = n0 + (lane & 15);
#pragma unroll
  for (int ns = 0; ns < 4; ++ns) {
#pragma unroll
    for (int r = 0; r < 4; ++r) {
      const int rg = r0 + r;
      const int cg = cb + (ns << 4);
      float v = acc[ns][r];
      float pv = __shfl_xor(v, 1);  // partner column of the RoPE pair
      const int t = rg & (T_ - 1);
      const int c = (MODE == 1) ? (cg & (C_ - 1)) : cg;
      const int i = c >> 1;
      const float cf = cosT[(t << 8) + i];
      const float sf = sinT[(t << 8) + i];
      float x1 = (lane & 1) ? pv : v;
      float x2 = (lane & 1) ? v : pv;
      float y = (lane & 1) ? (x1 * sf + x2 * cf) : (x1 * cf - x2 * sf);
      if (MODE == 1) y *= 0.044194173824159216f;  // 1/sqrt(512)
      const u16 hi = f2bf(y);
      const u16 lo = f2bf(y - bf2f(hi));
      size_t rowoff;
      if (MODE == 1) {
        const int b = rg >> 11, n = cg >> 9;
        rowoff = ((size_t)((b * NB_ + n) * T_ + t)) * C2_;
      } else {
        rowoff = (size_t)rg * C2_;
      }
      out[rowoff + c] = hi;
      out[rowoff + C_ + c] = lo;
    }
  }
}

// ---------------------------------------------------------------------------
// Plain hi-only GEMM: A f32 (AF32=1) or bf16, W f32; out bf16 or f32 (OF32).
// ---------------------------------------------------------------------------
template <int AF32, int OF32>
__global__ __launch_bounds__(256) void gemm_hi(const void* __restrict__ Ap,
                                               const float* __restrict__ W,
                                               void* __restrict__ outp,
                                               const int N, const int K) {
  __shared__ u16 As[64][32];
  __shared__ u16 Bs[64][32];
  const int tid = threadIdx.x;
  const int wave = tid >> 6, lane = tid & 63;
  const int m0 = blockIdx.y << 6, n0 = blockIdx.x << 6;
  const f32x4 zero = {0.f, 0.f, 0.f, 0.f};
  f32x4 acc[4] = {zero, zero, zero, zero};
  const int srow = tid >> 2, koff = ((tid & 3) << 3) ^ swz(tid >> 2);
  const int lrow = lane & 15, lk = ((lane >> 4) << 3) ^ swz(lane & 15);
  for (int kk = 0; kk < K; kk += 32) {
    const int kg = (tid & 3) << 3;
    if (AF32) {
      const float* A = (const float*)Ap;
      float av[8];
      *(float4*)(av) = *(const float4*)(&A[(size_t)(m0 + srow) * K + kk + kg]);
      *(float4*)(av + 4) =
          *(const float4*)(&A[(size_t)(m0 + srow) * K + kk + kg + 4]);
      uint4 hi;
      hi.x = f2bf(av[0]) | ((unsigned)f2bf(av[1]) << 16);
      hi.y = f2bf(av[2]) | ((unsigned)f2bf(av[3]) << 16);
      hi.z = f2bf(av[4]) | ((unsigned)f2bf(av[5]) << 16);
      hi.w = f2bf(av[6]) | ((unsigned)f2bf(av[7]) << 16);
      *(uint4*)(&As[srow][koff]) = hi;
    } else {
      const u16* A = (const u16*)Ap;
      *(uint4*)(&As[srow][koff]) =
          *(const uint4*)(&A[(size_t)(m0 + srow) * K + kk + kg]);
    }
    uint4 hi;
    {
      float w[8];
#pragma unroll
      for (int j = 0; j < 8; ++j)
        w[j] = W[(size_t)(kk + kg + j) * N + n0 + srow];
      hi.x = f2bf(w[0]) | ((unsigned)f2bf(w[1]) << 16);
      hi.y = f2bf(w[2]) | ((unsigned)f2bf(w[3]) << 16);
      hi.z = f2bf(w[4]) | ((unsigned)f2bf(w[5]) << 16);
      hi.w = f2bf(w[6]) | ((unsigned)f2bf(w[7]) << 16);
    }
    *(uint4*)(&Bs[srow][koff]) = hi;
    __syncthreads();
    short8 af = *(const short8*)(&As[(wave << 4) + lrow][lk]);
#pragma unroll
    for (int ns = 0; ns < 4; ++ns) {
      short8 bf = *(const short8*)(&Bs[(ns << 4) + lrow][lk]);
      acc[ns] = mfma16x16x32(af, bf, acc[ns]);
    }
    __syncthreads();
  }
  const int r0 = m0 + (wave << 4) + ((lane >> 4) << 2);
  const int cb = n0 + (lane & 15);
#pragma unroll
  for (int ns = 0; ns < 4; ++ns) {
#pragma unroll
    for (int r = 0; r < 4; ++r) {
      const size_t idx = (size_t)(r0 + r) * N + cb + (ns << 4);
      if (OF32) ((float*)outp)[idx] = acc[ns][r];
      else ((u16*)outp)[idx] = f2bf(acc[ns][r]);
    }
  }
}

// ---------------------------------------------------------------------------
// Vraw (B,T,NB*C) bf16 -> VT (B,NB,C,T) tiled transpose, 64x64 tiles.
// ---------------------------------------------------------------------------
__global__ __launch_bounds__(256) void transpose_v_k(const u16* __restrict__ Vraw,
                                                     u16* __restrict__ VT) {
  const int bid = blockIdx.x;
  const int ct = bid & 7;
  const int ttile = (bid >> 3) & 31;
  const int n = (bid >> 8) & 3;
  const int b = bid >> 10;
  __shared__ u16 tile[64][68];
  const int tid = threadIdx.x;
  const int rr = tid >> 4;
  const int cc = (tid & 15) << 2;
  const int t0 = ttile << 6, c0 = ct << 6;
#pragma unroll
  for (int it = 0; it < 4; ++it) {
    const int r = (it << 4) + rr;
    *(ushort4*)(&tile[r][cc]) = *(const ushort4*)(
        &Vraw[((size_t)((b << 11) + t0 + r)) * (NB_ * C_) + n * C_ + c0 + cc]);
  }
  __syncthreads();
#pragma unroll
  for (int it = 0; it < 4; ++it) {
    const int c = (it << 4) + rr;
    ushort4 w;
    w.x = tile[cc + 0][c]; w.y = tile[cc + 1][c];
    w.z = tile[cc + 2][c]; w.w = tile[cc + 3][c];
    *(ushort4*)(&VT[((size_t)((b * NB_ + n) * C_ + c0 + c)) * T_ + t0 + cc]) = w;
  }
}

// ---------------------------------------------------------------------------
// Scores (R18 = R14 proven form + XCD tri chunking): per lower-tri 64x64
// (t,s) tile, 4 branches, fused split segments (40KB LDS), swizzled LDS,
// __syncthreads lockstep. Writes M (bf16), Mask (u8).
// ---------------------------------------------------------------------------
__global__ __launch_bounds__(256) void scores_k(const u16* __restrict__ Qcat,
                                                const u16* __restrict__ Kcat,
                                                u16* __restrict__ Mout,
                                                u8* __restrict__ Mask) {
  // XCD-chunked swizzle: 8 XCDs x 66 consecutive tris each (528 = 8*66,
  // bijective; all scores blocks do identical work -> balance-neutral).
  const int tri = ((blockIdx.x & 7) * 66) + (blockIdx.x >> 3);
  int tt = (int)((sqrtf(8.f * (float)tri + 1.f) - 1.f) * 0.5f);
  while ((tt + 1) * (tt + 2) / 2 <= tri) ++tt;
  while (tt * (tt + 1) / 2 > tri) --tt;
  const int ss = tri - tt * (tt + 1) / 2;
  const int b = blockIdx.y;
  __shared__ u16 Qh[NB_][64][32], Ql[NB_][64][32];
  __shared__ u16 Kh[64][32], Kl[64][32];
  const int tid = threadIdx.x;
  const int wave = tid >> 6, lane = tid & 63;
  const int t0 = tt << 6, s0 = ss << 6;
  const f32x4 zero = {0.f, 0.f, 0.f, 0.f};
  f32x4 acc[NB_][4];
  for (int n = 0; n < NB_; ++n)
    for (int j = 0; j < 4; ++j) acc[n][j] = zero;
  const int srow = tid >> 2, koff = ((tid & 3) << 3) ^ swz(tid >> 2);
  const int lrow = lane & 15, lk = ((lane >> 4) << 3) ^ swz(lane & 15);
  const int kg = (tid & 3) << 3;
  for (int kk = 0; kk < C_; kk += 32) {
#pragma unroll
    for (int n = 0; n < NB_; ++n) {
      const size_t qb =
          ((size_t)((b * NB_ + n) * T_ + t0 + srow)) * C2_ + kk + kg;
      *(uint4*)(&Qh[n][srow][koff]) = *(const uint4*)(&Qcat[qb]);
      *(uint4*)(&Ql[n][srow][koff]) = *(const uint4*)(&Qcat[qb + C_]);
    }
    const size_t kb = ((size_t)((b << 11) + s0 + srow)) * C2_ + kk + kg;
    *(uint4*)(&Kh[srow][koff]) = *(const uint4*)(&Kcat[kb]);
    *(uint4*)(&Kl[srow][koff]) = *(const uint4*)(&Kcat[kb + C_]);
    __syncthreads();
    short8 qh[NB_], ql[NB_];
#pragma unroll
    for (int n = 0; n < NB_; ++n) {
      qh[n] = *(const short8*)(&Qh[n][(wave << 4) + lrow][lk]);
      ql[n] = *(const short8*)(&Ql[n][(wave << 4) + lrow][lk]);
    }
#pragma unroll
    for (int ns = 0; ns < 4; ++ns) {
      short8 kh = *(const short8*)(&Kh[(ns << 4) + lrow][lk]);
      short8 kl = *(const short8*)(&Kl[(ns << 4) + lrow][lk]);
#pragma unroll
      for (int n = 0; n < NB_; ++n) {
        acc[n][ns] = mfma16x16x32(qh[n], kh, acc[n][ns]);
        acc[n][ns] = mfma16x16x32(ql[n], kh, acc[n][ns]);
        acc[n][ns] = mfma16x16x32(qh[n], kl, acc[n][ns]);
      }
    }
    __syncthreads();
  }
  const int tb = t0 + (wave << 4) + ((lane >> 4) << 2);
  const int sb = s0 + (lane & 15);
#pragma unroll
  for (int ns = 0; ns < 4; ++ns) {
#pragma unroll
    for (int r = 0; r < 4; ++r) {
      const int t = tb + r, s = sb + (ns << 4);
      float a0 = acc[0][ns][r], a1 = acc[1][ns][r];
      float a2 = acc[2][ns][r], a3 = acc[3][ns][r];
      float m = fmaxf(fmaxf(a0, a1), fmaxf(a2, a3));
      u8 msk = (u8)((a0 == m) | ((a1 == m) << 1) | ((a2 == m) << 2) |
                    ((a3 == m) << 3));
      if (s > t) { m = -__builtin_inff(); msk = 0; }
      const size_t idx = (size_t)b * T_ * T_ + (size_t)t * T_ + s;
      Mout[idx] = f2bf(m);
      Mask[idx] = msk;
    }
  }
}

// ---------------------------------------------------------------------------
// Per-row softmax stats from bf16 M: rowmax, 1/sum(exp). One wave per (b,t).
// ---------------------------------------------------------------------------
__global__ __launch_bounds__(256) void rowstats_k(const u16* __restrict__ Mb,
                                                  float* __restrict__ Rm,
                                                  float* __restrict__ Rz) {
  const int r = (blockIdx.x << 2) + (threadIdx.x >> 6);
  const int lane = threadIdx.x & 63;
  const int b = r >> 11, t = r & (T_ - 1);
  const u16* row = Mb + (size_t)b * T_ * T_ + (size_t)t * T_;
  float m = -__builtin_inff();
  for (int s = lane; s <= t; s += 64) m = fmaxf(m, bf2f(row[s]));
#pragma unroll
  for (int off = 32; off; off >>= 1) m = fmaxf(m, __shfl_xor(m, off));
  float z = 0.f;
  for (int s = lane; s <= t; s += 64) z += expf(bf2f(row[s]) - m);
#pragma unroll
  for (int off = 32; off; off >>= 1) z += __shfl_xor(z, off);
  if (lane == 0) { Rm[r] = m; Rz[r] = 1.f / z; }
}

// ---------------------------------------------------------------------------
// Routed PV with FUSED P-build (R18): reads M (bf16) + per-row Rm/Rz and
// computes P = f2bf(exp(M-rm)*rz) inline at staging time (bit-identical
// rounding to the old pbuild_k). Paired tiles + c-split: grid (16,16,2);
// block x handles t-tiles x and 31-x (66 chunks, perfect balance); y picks a
// 32-wide c stripe. 2 blocks/CU. One-chunk register prefetch kept.
// ---------------------------------------------------------------------------
__global__ __launch_bounds__(256) void pv_k(const u16* __restrict__ Mb,
                                            const float* __restrict__ Rm,
                                            const float* __restrict__ Rz,
                                            const u8* __restrict__ Mask,
                                            const u16* __restrict__ VT,
                                            u16* __restrict__ Y) {
  const int ypair = blockIdx.x, cblk = blockIdx.y, b = blockIdx.z;
  const int c0 = cblk << 5;  // 32-wide c stripe
  __shared__ u16 Ps[NB_][64][32];
  __shared__ u16 Vs[NB_][32][32];
  const int tid = threadIdx.x;
  const int wave = tid >> 6, lane = tid & 63;
  const int prow = tid >> 2, soff = (tid & 3) << 3;   // global P sub-offset
  const int psoff = soff ^ swz(prow);                  // swizzled LDS col
  const int vrow = tid >> 3, vsoff = (tid & 7) << 2;  // global V sub-offset
  const int vcol = ((((tid & 7) >> 1) ^ ((vrow >> 1) & 3)) << 3) |
                   ((tid & 1) << 2);                   // swizzled LDS col
  const int lrow = lane & 15, lk = ((lane >> 4) << 3) ^ swz(lane & 15);
  const f32x4 zero = {0.f, 0.f, 0.f, 0.f};
  const size_t vrow_base[NB_] = {
      ((size_t)((b * NB_ + 0) * C_ + c0 + vrow)) * T_,
      ((size_t)((b * NB_ + 1) * C_ + c0 + vrow)) * T_,
      ((size_t)((b * NB_ + 2) * C_ + c0 + vrow)) * T_,
      ((size_t)((b * NB_ + 3) * C_ + c0 + vrow)) * T_};

  for (int half = 0; half < 2; ++half) {
    const int tt = half ? (31 - ypair) : ypair;
    const int t0 = tt << 6;
    const int nchunk = (tt + 1) << 1;
    const int rg = (b << 11) + t0 + prow;       // this thread's (b,t) row
    const size_t pro = (size_t)rg << 11;
    const float rm = Rm[rg], rz = Rz[rg];       // per-row scalars, once/half
    f32x4 acc[2] = {zero, zero};
    uint4 pu; uint2 mk2; uint2 vv[NB_];
    // prefetch chunk 0 (M values; converted to P at staging)
    pu = *(const uint4*)(&Mb[pro + soff]);
    mk2 = *(const uint2*)(&Mask[pro + soff]);
#pragma unroll
    for (int n = 0; n < NB_; ++n)
      vv[n] = *(const uint2*)(&VT[vrow_base[n] + vsoff]);
    for (int ck = 0; ck < nchunk; ++ck) {
      u16 m8[8] = {(u16)pu.x, (u16)(pu.x >> 16), (u16)pu.y, (u16)(pu.y >> 16),
                   (u16)pu.z, (u16)(pu.z >> 16), (u16)pu.w, (u16)(pu.w >> 16)};
      u16 p[8];
#pragma unroll
      for (int j = 0; j < 8; ++j)
        p[j] = f2bf(expf(bf2f(m8[j]) - rm) * rz);  // == old pbuild rounding
      u8 mk[8] = {(u8)mk2.x, (u8)(mk2.x >> 8), (u8)(mk2.x >> 16),
                  (u8)(mk2.x >> 24), (u8)mk2.y, (u8)(mk2.y >> 8),
                  (u8)(mk2.y >> 16), (u8)(mk2.y >> 24)};
#pragma unroll
      for (int n = 0; n < NB_; ++n) {
        uint4 wv;
        wv.x = (unsigned)(((mk[0] >> n) & 1) ? p[0] : 0) |
               ((unsigned)(((mk[1] >> n) & 1) ? p[1] : 0) << 16);
        wv.y = (unsigned)(((mk[2] >> n) & 1) ? p[2] : 0) |
               ((unsigned)(((mk[3] >> n) & 1) ? p[3] : 0) << 16);
        wv.z = (unsigned)(((mk[4] >> n) & 1) ? p[4] : 0) |
               ((unsigned)(((mk[5] >> n) & 1) ? p[5] : 0) << 16);
        wv.w = (unsigned)(((mk[6] >> n) & 1) ? p[6] : 0) |
               ((unsigned)(((mk[7] >> n) & 1) ? p[7] : 0) << 16);
        *(uint4*)(&Ps[n][prow][psoff]) = wv;
        *(uint2*)(&Vs[n][vrow][vcol]) = vv[n];
      }
      __syncthreads();
      if (ck + 1 < nchunk) {  // prefetch next chunk (overlaps MFMA)
        const int sB = (ck + 1) << 5;
        pu = *(const uint4*)(&Mb[pro + sB + soff]);
        mk2 = *(const uint2*)(&Mask[pro + sB + soff]);
#pragma unroll
        for (int n = 0; n < NB_; ++n)
          vv[n] = *(const uint2*)(&VT[vrow_base[n] + sB + vsoff]);
      }
#pragma unroll
      for (int n = 0; n < NB_; ++n) {
        short8 af = *(const short8*)(&Ps[n][(wave << 4) + lrow][lk]);
#pragma unroll
        for (int cs = 0; cs < 2; ++cs) {
          short8 bf = *(const short8*)(&Vs[n][(cs << 4) + lrow][lk]);
          acc[cs] = mfma16x16x32(af, bf, acc[cs]);
        }
      }
      __syncthreads();
    }
    const int tb = t0 + (wave << 4) + ((lane >> 4) << 2);
    const int cbs = c0 + (lane & 15);
#pragma unroll
    for (int cs = 0; cs < 2; ++cs) {
#pragma unroll
      for (int r = 0; r < 4; ++r) {
        Y[(size_t)((b << 11) + tb + r) * C_ + cbs + (cs << 4)] =
            f2bf(acc[cs][r]);
      }
    }
  }
}

// ---------------------------------------------------------------------------
extern "C" void kernel_launch(void* const* d_in, const int* in_sizes, int n_in,
                              void* d_out, int out_size, void* d_ws,
                              size_t ws_size, hipStream_t stream) {
  (void)in_sizes; (void)n_in; (void)out_size; (void)ws_size;
  const float* a    = (const float*)d_in[0];
  const float* x    = (const float*)d_in[1];
  const float* Wq   = (const float*)d_in[2];
  const float* Wk   = (const float*)d_in[3];
  const float* Wv   = (const float*)d_in[4];
  const float* Wo   = (const float*)d_in[5];
  const float* cosT = (const float*)d_in[6];
  const float* sinT = (const float*)d_in[7];

  char* w = (char*)d_ws;
  u16* Qcat   = (u16*)(w + 0);           // 33.5MB -> first 4.2MB reused as Y
  u16* Kcat   = (u16*)(w + 33554432);    //  8.4MB
  u16* Vraw   = (u16*)(w + 41943040);    // 16.8MB -> reused as bf16 M
  u16* VT     = (u16*)(w + 58720256);    // 16.8MB
  u8*  Mask   = (u8*)(w + 75497472);     //  8.4MB
  float* Rm   = (float*)(w + 83886080);  //  16KB
  float* Rz   = (float*)(w + 83902464);  //  16KB
  u16* Mb     = Vraw;
  u16* Y      = Qcat;

  const dim3 blk(256);
  gemm_qk<1><<<dim3(32, 64), blk, 0, stream>>>(a, Wq, Qcat, cosT, sinT, 2048, 512);
  gemm_qk<2><<<dim3(8, 64), blk, 0, stream>>>(x, Wk, Kcat, cosT, sinT, 512, 512);
  gemm_hi<1, 0><<<dim3(32, 64), blk, 0, stream>>>(a, Wv, (void*)Vraw, 2048, 512);
  transpose_v_k<<<dim3(2048), blk, 0, stream>>>(Vraw, VT);
  scores_k<<<dim3(528, 2), blk, 0, stream>>>(Qcat, Kcat, Mb, Mask);
  rowstats_k<<<dim3(1024), blk, 0, stream>>>(Mb, Rm, Rz);
  pv_k<<<dim3(16, 16, 2), blk, 0, stream>>>(Mb, Rm, Rz, Mask, VT, Y);
  gemm_hi<0, 1><<<dim3(8, 64), blk, 0, stream>>>(Y, Wo, d_out, 512, 512);
}

// Round 7
// 370.981 us; speedup vs baseline: 1.0589x; 1.0363x over previous
//
#include <hip/hip_runtime.h>
#include <math.h>

// ============================================================================
// R19: R18 base (384.4us) + fast-path exp in pv_k and rowstats_k.
// R18 post-mortem: fusion netted -8us but pv_k 76->103.8us, VALUBusy 61% --
// libm expf = ~20-instr __ocml sequence, x8/thread/chunk, and replicated 16x
// across c-stripe blocks. Fix: __expf (v_mul by log2e + v_exp_f32, one
// 4-cycle transcendental). ~5x less exp VALU. Numerics: ~2ulp f32 difference,
// quantized to bf16 and damped by the PV dot -> far below 0.015625 tolerance.
// Same switch in rowstats_k.
// Predicted: pv VALU 61->~32%, dur 103.8->~80us, total -> ~360us.
// ============================================================================

#define B_ 2
#define T_ 2048
#define C_ 512
#define NB_ 4
#define C2_ 1024  // hi|lo row width for Qcat/Kcat

typedef unsigned short u16;
typedef unsigned char u8;
using short8 = __attribute__((ext_vector_type(8))) short;
using bf16x8 = __attribute__((ext_vector_type(8))) __bf16;
using f32x4  = __attribute__((ext_vector_type(4))) float;

__device__ __forceinline__ float bf2f(u16 u) {
  union { unsigned int i; float f; } v; v.i = ((unsigned int)u) << 16; return v.f;
}
__device__ __forceinline__ u16 f2bf(float f) {  // round-to-nearest-even
  union { float f; unsigned int i; } v; v.f = f;
  unsigned int u = v.i;
  return (u16)((u + 0x7fffu + ((u >> 16) & 1u)) >> 16);
}
__device__ __forceinline__ f32x4 mfma16x16x32(short8 a, short8 b, f32x4 c) {
  return __builtin_amdgcn_mfma_f32_16x16x32_bf16(
      __builtin_bit_cast(bf16x8, a), __builtin_bit_cast(bf16x8, b), c, 0, 0, 0);
}
__device__ __forceinline__ void split8(const float* s, uint4& hi, uint4& lo) {
  u16 h[8], l[8];
#pragma unroll
  for (int j = 0; j < 8; ++j) {
    h[j] = f2bf(s[j]);
    l[j] = f2bf(s[j] - bf2f(h[j]));
  }
  hi.x = h[0] | ((unsigned)h[1] << 16); hi.y = h[2] | ((unsigned)h[3] << 16);
  hi.z = h[4] | ((unsigned)h[5] << 16); hi.w = h[6] | ((unsigned)h[7] << 16);
  lo.x = l[0] | ((unsigned)l[1] << 16); lo.y = l[2] | ((unsigned)l[3] << 16);
  lo.z = l[4] | ((unsigned)l[5] << 16); lo.w = l[6] | ((unsigned)l[7] << 16);
}
// LDS bank swizzle: XOR the 16B column-group with row bits [2:1].
__device__ __forceinline__ int swz(int row) { return ((row >> 1) & 3) << 3; }

// ---------------------------------------------------------------------------
// Split-precision 64x64 GEMM with fused RoPE epilogue (R8 version).
// MODE 1: +1/sqrt(C) scale -> Qcat (B,NB,T,[hi512|lo512]).
// MODE 2: -> Kcat (B*T,[hi512|lo512]).
// ---------------------------------------------------------------------------
template <int MODE>
__global__ __launch_bounds__(256) void gemm_qk(const float* __restrict__ A,
                                               const float* __restrict__ W,
                                               u16* __restrict__ out,
                                               const float* __restrict__ cosT,
                                               const float* __restrict__ sinT,
                                               const int N, const int K) {
  __shared__ u16 Ah[64][32], Al[64][32];
  __shared__ u16 Bh[64][32], Bl[64][32];  // [n][k]
  const int tid = threadIdx.x;
  const int wave = tid >> 6, lane = tid & 63;
  const int m0 = blockIdx.y << 6, n0 = blockIdx.x << 6;
  const f32x4 zero = {0.f, 0.f, 0.f, 0.f};
  f32x4 acc[4] = {zero, zero, zero, zero};
  const int srow = tid >> 2, koff = ((tid & 3) << 3) ^ swz(tid >> 2);
  const int lrow = lane & 15, lk = ((lane >> 4) << 3) ^ swz(lane & 15);
  for (int kk = 0; kk < K; kk += 32) {
    const int kg = (tid & 3) << 3;  // global k sub-offset (unswizzled)
    float av[8];
    *(float4*)(av) = *(const float4*)(&A[(size_t)(m0 + srow) * K + kk + kg]);
    *(float4*)(av + 4) =
        *(const float4*)(&A[(size_t)(m0 + srow) * K + kk + kg + 4]);
    uint4 hi, lo;
    split8(av, hi, lo);
    *(uint4*)(&Ah[srow][koff]) = hi;
    *(uint4*)(&Al[srow][koff]) = lo;
    float wv[8];
#pragma unroll
    for (int j = 0; j < 8; ++j)
      wv[j] = W[(size_t)(kk + kg + j) * N + n0 + srow];
    split8(wv, hi, lo);
    *(uint4*)(&Bh[srow][koff]) = hi;
    *(uint4*)(&Bl[srow][koff]) = lo;
    __syncthreads();
    short8 ah = *(const short8*)(&Ah[(wave << 4) + lrow][lk]);
    short8 al = *(const short8*)(&Al[(wave << 4) + lrow][lk]);
#pragma unroll
    for (int ns = 0; ns < 4; ++ns) {
      short8 bh = *(const short8*)(&Bh[(ns << 4) + lrow][lk]);
      short8 bl = *(const short8*)(&Bl[(ns << 4) + lrow][lk]);
      acc[ns] = mfma16x16x32(ah, bh, acc[ns]);
      acc[ns] = mfma16x16x32(al, bh, acc[ns]);
      acc[ns] = mfma16x16x32(ah, bl, acc[ns]);
    }
    __syncthreads();
  }
  const int r0 = m0 + (wave << 4) + ((lane >> 4) << 2);
  const int cb = n0 + (lane & 15);
#pragma unroll
  for (int ns = 0; ns < 4; ++ns) {
#pragma unroll
    for (int r = 0; r < 4; ++r) {
      const int rg = r0 + r;
      const int cg = cb + (ns << 4);
      float v = acc[ns][r];
      float pv = __shfl_xor(v, 1);  // partner column of the RoPE pair
      const int t = rg & (T_ - 1);
      const int c = (MODE == 1) ? (cg & (C_ - 1)) : cg;
      const int i = c >> 1;
      const float cf = cosT[(t << 8) + i];
      const float sf = sinT[(t << 8) + i];
      float x1 = (lane & 1) ? pv : v;
      float x2 = (lane & 1) ? v : pv;
      float y = (lane & 1) ? (x1 * sf + x2 * cf) : (x1 * cf - x2 * sf);
      if (MODE == 1) y *= 0.044194173824159216f;  // 1/sqrt(512)
      const u16 hi = f2bf(y);
      const u16 lo = f2bf(y - bf2f(hi));
      size_t rowoff;
      if (MODE == 1) {
        const int b = rg >> 11, n = cg >> 9;
        rowoff = ((size_t)((b * NB_ + n) * T_ + t)) * C2_;
      } else {
        rowoff = (size_t)rg * C2_;
      }
      out[rowoff + c] = hi;
      out[rowoff + C_ + c] = lo;
    }
  }
}

// ---------------------------------------------------------------------------
// Plain hi-only GEMM: A f32 (AF32=1) or bf16, W f32; out bf16 or f32 (OF32).
// ---------------------------------------------------------------------------
template <int AF32, int OF32>
__global__ __launch_bounds__(256) void gemm_hi(const void* __restrict__ Ap,
                                               const float* __restrict__ W,
                                               void* __restrict__ outp,
                                               const int N, const int K) {
  __shared__ u16 As[64][32];
  __shared__ u16 Bs[64][32];
  const int tid = threadIdx.x;
  const int wave = tid >> 6, lane = tid & 63;
  const int m0 = blockIdx.y << 6, n0 = blockIdx.x << 6;
  const f32x4 zero = {0.f, 0.f, 0.f, 0.f};
  f32x4 acc[4] = {zero, zero, zero, zero};
  const int srow = tid >> 2, koff = ((tid & 3) << 3) ^ swz(tid >> 2);
  const int lrow = lane & 15, lk = ((lane >> 4) << 3) ^ swz(lane & 15);
  for (int kk = 0; kk < K; kk += 32) {
    const int kg = (tid & 3) << 3;
    if (AF32) {
      const float* A = (const float*)Ap;
      float av[8];
      *(float4*)(av) = *(const float4*)(&A[(size_t)(m0 + srow) * K + kk + kg]);
      *(float4*)(av + 4) =
          *(const float4*)(&A[(size_t)(m0 + srow) * K + kk + kg + 4]);
      uint4 hi;
      hi.x = f2bf(av[0]) | ((unsigned)f2bf(av[1]) << 16);
      hi.y = f2bf(av[2]) | ((unsigned)f2bf(av[3]) << 16);
      hi.z = f2bf(av[4]) | ((unsigned)f2bf(av[5]) << 16);
      hi.w = f2bf(av[6]) | ((unsigned)f2bf(av[7]) << 16);
      *(uint4*)(&As[srow][koff]) = hi;
    } else {
      const u16* A = (const u16*)Ap;
      *(uint4*)(&As[srow][koff]) =
          *(const uint4*)(&A[(size_t)(m0 + srow) * K + kk + kg]);
    }
    uint4 hi;
    {
      float w[8];
#pragma unroll
      for (int j = 0; j < 8; ++j)
        w[j] = W[(size_t)(kk + kg + j) * N + n0 + srow];
      hi.x = f2bf(w[0]) | ((unsigned)f2bf(w[1]) << 16);
      hi.y = f2bf(w[2]) | ((unsigned)f2bf(w[3]) << 16);
      hi.z = f2bf(w[4]) | ((unsigned)f2bf(w[5]) << 16);
      hi.w = f2bf(w[6]) | ((unsigned)f2bf(w[7]) << 16);
    }
    *(uint4*)(&Bs[srow][koff]) = hi;
    __syncthreads();
    short8 af = *(const short8*)(&As[(wave << 4) + lrow][lk]);
#pragma unroll
    for (int ns = 0; ns < 4; ++ns) {
      short8 bf = *(const short8*)(&Bs[(ns << 4) + lrow][lk]);
      acc[ns] = mfma16x16x32(af, bf, acc[ns]);
    }
    __syncthreads();
  }
  const int r0 = m0 + (wave << 4) + ((lane >> 4) << 2);
  const int cb = n0 + (lane & 15);
#pragma unroll
  for (int ns = 0; ns < 4; ++ns) {
#pragma unroll
    for (int r = 0; r < 4; ++r) {
      const size_t idx = (size_t)(r0 + r) * N + cb + (ns << 4);
      if (OF32) ((float*)outp)[idx] = acc[ns][r];
      else ((u16*)outp)[idx] = f2bf(acc[ns][r]);
    }
  }
}

// ---------------------------------------------------------------------------
// Vraw (B,T,NB*C) bf16 -> VT (B,NB,C,T) tiled transpose, 64x64 tiles.
// ---------------------------------------------------------------------------
__global__ __launch_bounds__(256) void transpose_v_k(const u16* __restrict__ Vraw,
                                                     u16* __restrict__ VT) {
  const int bid = blockIdx.x;
  const int ct = bid & 7;
  const int ttile = (bid >> 3) & 31;
  const int n = (bid >> 8) & 3;
  const int b = bid >> 10;
  __shared__ u16 tile[64][68];
  const int tid = threadIdx.x;
  const int rr = tid >> 4;
  const int cc = (tid & 15) << 2;
  const int t0 = ttile << 6, c0 = ct << 6;
#pragma unroll
  for (int it = 0; it < 4; ++it) {
    const int r = (it << 4) + rr;
    *(ushort4*)(&tile[r][cc]) = *(const ushort4*)(
        &Vraw[((size_t)((b << 11) + t0 + r)) * (NB_ * C_) + n * C_ + c0 + cc]);
  }
  __syncthreads();
#pragma unroll
  for (int it = 0; it < 4; ++it) {
    const int c = (it << 4) + rr;
    ushort4 w;
    w.x = tile[cc + 0][c]; w.y = tile[cc + 1][c];
    w.z = tile[cc + 2][c]; w.w = tile[cc + 3][c];
    *(ushort4*)(&VT[((size_t)((b * NB_ + n) * C_ + c0 + c)) * T_ + t0 + cc]) = w;
  }
}

// ---------------------------------------------------------------------------
// Scores (R18 form): per lower-tri 64x64 (t,s) tile, 4 branches, fused split
// segments (40KB LDS), swizzled LDS, XCD-chunked tri swizzle.
// ---------------------------------------------------------------------------
__global__ __launch_bounds__(256) void scores_k(const u16* __restrict__ Qcat,
                                                const u16* __restrict__ Kcat,
                                                u16* __restrict__ Mout,
                                                u8* __restrict__ Mask) {
  // XCD-chunked swizzle: 8 XCDs x 66 consecutive tris each (bijective).
  const int tri = ((blockIdx.x & 7) * 66) + (blockIdx.x >> 3);
  int tt = (int)((sqrtf(8.f * (float)tri + 1.f) - 1.f) * 0.5f);
  while ((tt + 1) * (tt + 2) / 2 <= tri) ++tt;
  while (tt * (tt + 1) / 2 > tri) --tt;
  const int ss = tri - tt * (tt + 1) / 2;
  const int b = blockIdx.y;
  __shared__ u16 Qh[NB_][64][32], Ql[NB_][64][32];
  __shared__ u16 Kh[64][32], Kl[64][32];
  const int tid = threadIdx.x;
  const int wave = tid >> 6, lane = tid & 63;
  const int t0 = tt << 6, s0 = ss << 6;
  const f32x4 zero = {0.f, 0.f, 0.f, 0.f};
  f32x4 acc[NB_][4];
  for (int n = 0; n < NB_; ++n)
    for (int j = 0; j < 4; ++j) acc[n][j] = zero;
  const int srow = tid >> 2, koff = ((tid & 3) << 3) ^ swz(tid >> 2);
  const int lrow = lane & 15, lk = ((lane >> 4) << 3) ^ swz(lane & 15);
  const int kg = (tid & 3) << 3;
  for (int kk = 0; kk < C_; kk += 32) {
#pragma unroll
    for (int n = 0; n < NB_; ++n) {
      const size_t qb =
          ((size_t)((b * NB_ + n) * T_ + t0 + srow)) * C2_ + kk + kg;
      *(uint4*)(&Qh[n][srow][koff]) = *(const uint4*)(&Qcat[qb]);
      *(uint4*)(&Ql[n][srow][koff]) = *(const uint4*)(&Qcat[qb + C_]);
    }
    const size_t kb = ((size_t)((b << 11) + s0 + srow)) * C2_ + kk + kg;
    *(uint4*)(&Kh[srow][koff]) = *(const uint4*)(&Kcat[kb]);
    *(uint4*)(&Kl[srow][koff]) = *(const uint4*)(&Kcat[kb + C_]);
    __syncthreads();
    short8 qh[NB_], ql[NB_];
#pragma unroll
    for (int n = 0; n < NB_; ++n) {
      qh[n] = *(const short8*)(&Qh[n][(wave << 4) + lrow][lk]);
      ql[n] = *(const short8*)(&Ql[n][(wave << 4) + lrow][lk]);
    }
#pragma unroll
    for (int ns = 0; ns < 4; ++ns) {
      short8 kh = *(const short8*)(&Kh[(ns << 4) + lrow][lk]);
      short8 kl = *(const short8*)(&Kl[(ns << 4) + lrow][lk]);
#pragma unroll
      for (int n = 0; n < NB_; ++n) {
        acc[n][ns] = mfma16x16x32(qh[n], kh, acc[n][ns]);
        acc[n][ns] = mfma16x16x32(ql[n], kh, acc[n][ns]);
        acc[n][ns] = mfma16x16x32(qh[n], kl, acc[n][ns]);
      }
    }
    __syncthreads();
  }
  const int tb = t0 + (wave << 4) + ((lane >> 4) << 2);
  const int sb = s0 + (lane & 15);
#pragma unroll
  for (int ns = 0; ns < 4; ++ns) {
#pragma unroll
    for (int r = 0; r < 4; ++r) {
      const int t = tb + r, s = sb + (ns << 4);
      float a0 = acc[0][ns][r], a1 = acc[1][ns][r];
      float a2 = acc[2][ns][r], a3 = acc[3][ns][r];
      float m = fmaxf(fmaxf(a0, a1), fmaxf(a2, a3));
      u8 msk = (u8)((a0 == m) | ((a1 == m) << 1) | ((a2 == m) << 2) |
                    ((a3 == m) << 3));
      if (s > t) { m = -__builtin_inff(); msk = 0; }
      const size_t idx = (size_t)b * T_ * T_ + (size_t)t * T_ + s;
      Mout[idx] = f2bf(m);
      Mask[idx] = msk;
    }
  }
}

// ---------------------------------------------------------------------------
// Per-row softmax stats from bf16 M: rowmax, 1/sum(exp). One wave per (b,t).
// R19: __expf fast path.
// ---------------------------------------------------------------------------
__global__ __launch_bounds__(256) void rowstats_k(const u16* __restrict__ Mb,
                                                  float* __restrict__ Rm,
                                                  float* __restrict__ Rz) {
  const int r = (blockIdx.x << 2) + (threadIdx.x >> 6);
  const int lane = threadIdx.x & 63;
  const int b = r >> 11, t = r & (T_ - 1);
  const u16* row = Mb + (size_t)b * T_ * T_ + (size_t)t * T_;
  float m = -__builtin_inff();
  for (int s = lane; s <= t; s += 64) m = fmaxf(m, bf2f(row[s]));
#pragma unroll
  for (int off = 32; off; off >>= 1) m = fmaxf(m, __shfl_xor(m, off));
  float z = 0.f;
  for (int s = lane; s <= t; s += 64) z += __expf(bf2f(row[s]) - m);
#pragma unroll
  for (int off = 32; off; off >>= 1) z += __shfl_xor(z, off);
  if (lane == 0) { Rm[r] = m; Rz[r] = 1.f / z; }
}

// ---------------------------------------------------------------------------
// Routed PV with FUSED P-build (R18) + fast exp (R19): P = f2bf(__expf(M-rm)
// *rz) inline at staging (v_exp_f32 path, ~5x fewer VALU than libm expf).
// Paired tiles + c-split: grid (16,16,2). 2 blocks/CU. LDS 24KB.
// ---------------------------------------------------------------------------
__global__ __launch_bounds__(256) void pv_k(const u16* __restrict__ Mb,
                                            const float* __restrict__ Rm,
                                            const float* __restrict__ Rz,
                                            const u8* __restrict__ Mask,
                                            const u16* __restrict__ VT,
                                            u16* __restrict__ Y) {
  const int ypair = blockIdx.x, cblk = blockIdx.y, b = blockIdx.z;
  const int c0 = cblk << 5;  // 32-wide c stripe
  __shared__ u16 Ps[NB_][64][32];
  __shared__ u16 Vs[NB_][32][32];
  const int tid = threadIdx.x;
  const int wave = tid >> 6, lane = tid & 63;
  const int prow = tid >> 2, soff = (tid & 3) << 3;   // global P sub-offset
  const int psoff = soff ^ swz(prow);                  // swizzled LDS col
  const int vrow = tid >> 3, vsoff = (tid & 7) << 2;  // global V sub-offset
  const int vcol = ((((tid & 7) >> 1) ^ ((vrow >> 1) & 3)) << 3) |
                   ((tid & 1) << 2);                   // swizzled LDS col
  const int lrow = lane & 15, lk = ((lane >> 4) << 3) ^ swz(lane & 15);
  const f32x4 zero = {0.f, 0.f, 0.f, 0.f};
  const size_t vrow_base[NB_] = {
      ((size_t)((b * NB_ + 0) * C_ + c0 + vrow)) * T_,
      ((size_t)((b * NB_ + 1) * C_ + c0 + vrow)) * T_,
      ((size_t)((b * NB_ + 2) * C_ + c0 + vrow)) * T_,
      ((size_t)((b * NB_ + 3) * C_ + c0 + vrow)) * T_};

  for (int half = 0; half < 2; ++half) {
    const int tt = half ? (31 - ypair) : ypair;
    const int t0 = tt << 6;
    const int nchunk = (tt + 1) << 1;
    const int rg = (b << 11) + t0 + prow;       // this thread's (b,t) row
    const size_t pro = (size_t)rg << 11;
    const float rm = Rm[rg], rz = Rz[rg];       // per-row scalars, once/half
    f32x4 acc[2] = {zero, zero};
    uint4 pu; uint2 mk2; uint2 vv[NB_];
    // prefetch chunk 0 (M values; converted to P at staging)
    pu = *(const uint4*)(&Mb[pro + soff]);
    mk2 = *(const uint2*)(&Mask[pro + soff]);
#pragma unroll
    for (int n = 0; n < NB_; ++n)
      vv[n] = *(const uint2*)(&VT[vrow_base[n] + vsoff]);
    for (int ck = 0; ck < nchunk; ++ck) {
      u16 m8[8] = {(u16)pu.x, (u16)(pu.x >> 16), (u16)pu.y, (u16)(pu.y >> 16),
                   (u16)pu.z, (u16)(pu.z >> 16), (u16)pu.w, (u16)(pu.w >> 16)};
      u16 p[8];
#pragma unroll
      for (int j = 0; j < 8; ++j)
        p[j] = f2bf(__expf(bf2f(m8[j]) - rm) * rz);  // v_exp_f32 fast path
      u8 mk[8] = {(u8)mk2.x, (u8)(mk2.x >> 8), (u8)(mk2.x >> 16),
                  (u8)(mk2.x >> 24), (u8)mk2.y, (u8)(mk2.y >> 8),
                  (u8)(mk2.y >> 16), (u8)(mk2.y >> 24)};
#pragma unroll
      for (int n = 0; n < NB_; ++n) {
        uint4 wv;
        wv.x = (unsigned)(((mk[0] >> n) & 1) ? p[0] : 0) |
               ((unsigned)(((mk[1] >> n) & 1) ? p[1] : 0) << 16);
        wv.y = (unsigned)(((mk[2] >> n) & 1) ? p[2] : 0) |
               ((unsigned)(((mk[3] >> n) & 1) ? p[3] : 0) << 16);
        wv.z = (unsigned)(((mk[4] >> n) & 1) ? p[4] : 0) |
               ((unsigned)(((mk[5] >> n) & 1) ? p[5] : 0) << 16);
        wv.w = (unsigned)(((mk[6] >> n) & 1) ? p[6] : 0) |
               ((unsigned)(((mk[7] >> n) & 1) ? p[7] : 0) << 16);
        *(uint4*)(&Ps[n][prow][psoff]) = wv;
        *(uint2*)(&Vs[n][vrow][vcol]) = vv[n];
      }
      __syncthreads();
      if (ck + 1 < nchunk) {  // prefetch next chunk (overlaps MFMA)
        const int sB = (ck + 1) << 5;
        pu = *(const uint4*)(&Mb[pro + sB + soff]);
        mk2 = *(const uint2*)(&Mask[pro + sB + soff]);
#pragma unroll
        for (int n = 0; n < NB_; ++n)
          vv[n] = *(const uint2*)(&VT[vrow_base[n] + sB + vsoff]);
      }
#pragma unroll
      for (int n = 0; n < NB_; ++n) {
        short8 af = *(const short8*)(&Ps[n][(wave << 4) + lrow][lk]);
#pragma unroll
        for (int cs = 0; cs < 2; ++cs) {
          short8 bf = *(const short8*)(&Vs[n][(cs << 4) + lrow][lk]);
          acc[cs] = mfma16x16x32(af, bf, acc[cs]);
        }
      }
      __syncthreads();
    }
    const int tb = t0 + (wave << 4) + ((lane >> 4) << 2);
    const int cbs = c0 + (lane & 15);
#pragma unroll
    for (int cs = 0; cs < 2; ++cs) {
#pragma unroll
      for (int r = 0; r < 4; ++r) {
        Y[(size_t)((b << 11) + tb + r) * C_ + cbs + (cs << 4)] =
            f2bf(acc[cs][r]);
      }
    }
  }
}

// ---------------------------------------------------------------------------
extern "C" void kernel_launch(void* const* d_in, const int* in_sizes, int n_in,
                              void* d_out, int out_size, void* d_ws,
                              size_t ws_size, hipStream_t stream) {
  (void)in_sizes; (void)n_in; (void)out_size; (void)ws_size;
  const float* a    = (const float*)d_in[0];
  const float* x    = (const float*)d_in[1];
  const float* Wq   = (const float*)d_in[2];
  const float* Wk   = (const float*)d_in[3];
  const float* Wv   = (const float*)d_in[4];
  const float* Wo   = (const float*)d_in[5];
  const float* cosT = (const float*)d_in[6];
  const float* sinT = (const float*)d_in[7];

  char* w = (char*)d_ws;
  u16* Qcat   = (u16*)(w + 0);           // 33.5MB -> first 4.2MB reused as Y
  u16* Kcat   = (u16*)(w + 33554432);    //  8.4MB
  u16* Vraw   = (u16*)(w + 41943040);    // 16.8MB -> reused as bf16 M
  u16* VT     = (u16*)(w + 58720256);    // 16.8MB
  u8*  Mask   = (u8*)(w + 75497472);     //  8.4MB
  float* Rm   = (float*)(w + 83886080);  //  16KB
  float* Rz   = (float*)(w + 83902464);  //  16KB
  u16* Mb     = Vraw;
  u16* Y      = Qcat;

  const dim3 blk(256);
  gemm_qk<1><<<dim3(32, 64), blk, 0, stream>>>(a, Wq, Qcat, cosT, sinT, 2048, 512);
  gemm_qk<2><<<dim3(8, 64), blk, 0, stream>>>(x, Wk, Kcat, cosT, sinT, 512, 512);
  gemm_hi<1, 0><<<dim3(32, 64), blk, 0, stream>>>(a, Wv, (void*)Vraw, 2048, 512);
  transpose_v_k<<<dim3(2048), blk, 0, stream>>>(Vraw, VT);
  scores_k<<<dim3(528, 2), blk, 0, stream>>>(Qcat, Kcat, Mb, Mask);
  rowstats_k<<<dim3(1024), blk, 0, stream>>>(Mb, Rm, Rz);
  pv_k<<<dim3(16, 16, 2), blk, 0, stream>>>(Mb, Rm, Rz, Mask, VT, Y);
  gemm_hi<0, 1><<<dim3(8, 64), blk, 0, stream>>>(Y, Wo, d_out, 512, 512);
}

// Round 8
// 364.665 us; speedup vs baseline: 1.0773x; 1.0173x over previous
//
#include <hip/hip_runtime.h>
#include <math.h>

// ============================================================================
// R20: R19 base (371.0us) + pv_k replication halving.
// R19 post-mortem: pv 103.8->85.3 (exp fix 1:1 with prediction). Still
// VALU 50 / Mfma 8 / HBM 19 -> staging VALU dominates, and it's REPLICATED
// 16x (every 32-wide c-block recomputes the same routed-P row).
// Fix: 512-thread blocks, 64-wide c, grid (16,8,2)=256 blocks, 8 waves/CU
// (same wave count as before). P-staging per chunk now shared across 2x the
// output -> replication 16->8, per-thread staging uint4->uint2, M/Mask L2
// traffic halved. MFMA per wave unchanged. LDS 32KB. Same paired-tile
// balance, one-chunk prefetch, uniform col^swz(row) swizzle.
// Predicted: pv VALU ->~35%, dur 85.3->~62-70us, total ->~348-358us.
// ============================================================================

#define B_ 2
#define T_ 2048
#define C_ 512
#define NB_ 4
#define C2_ 1024  // hi|lo row width for Qcat/Kcat

typedef unsigned short u16;
typedef unsigned char u8;
using short8 = __attribute__((ext_vector_type(8))) short;
using bf16x8 = __attribute__((ext_vector_type(8))) __bf16;
using f32x4  = __attribute__((ext_vector_type(4))) float;

__device__ __forceinline__ float bf2f(u16 u) {
  union { unsigned int i; float f; } v; v.i = ((unsigned int)u) << 16; return v.f;
}
__device__ __forceinline__ u16 f2bf(float f) {  // round-to-nearest-even
  union { float f; unsigned int i; } v; v.f = f;
  unsigned int u = v.i;
  return (u16)((u + 0x7fffu + ((u >> 16) & 1u)) >> 16);
}
__device__ __forceinline__ f32x4 mfma16x16x32(short8 a, short8 b, f32x4 c) {
  return __builtin_amdgcn_mfma_f32_16x16x32_bf16(
      __builtin_bit_cast(bf16x8, a), __builtin_bit_cast(bf16x8, b), c, 0, 0, 0);
}
__device__ __forceinline__ void split8(const float* s, uint4& hi, uint4& lo) {
  u16 h[8], l[8];
#pragma unroll
  for (int j = 0; j < 8; ++j) {
    h[j] = f2bf(s[j]);
    l[j] = f2bf(s[j] - bf2f(h[j]));
  }
  hi.x = h[0] | ((unsigned)h[1] << 16); hi.y = h[2] | ((unsigned)h[3] << 16);
  hi.z = h[4] | ((unsigned)h[5] << 16); hi.w = h[6] | ((unsigned)h[7] << 16);
  lo.x = l[0] | ((unsigned)l[1] << 16); lo.y = l[2] | ((unsigned)l[3] << 16);
  lo.z = l[4] | ((unsigned)l[5] << 16); lo.w = l[6] | ((unsigned)l[7] << 16);
}
// LDS bank swizzle: XOR the 16B column-group with row bits [2:1].
__device__ __forceinline__ int swz(int row) { return ((row >> 1) & 3) << 3; }

// ---------------------------------------------------------------------------
// Split-precision 64x64 GEMM with fused RoPE epilogue (R8 version).
// MODE 1: +1/sqrt(C) scale -> Qcat (B,NB,T,[hi512|lo512]).
// MODE 2: -> Kcat (B*T,[hi512|lo512]).
// ---------------------------------------------------------------------------
template <int MODE>
__global__ __launch_bounds__(256) void gemm_qk(const float* __restrict__ A,
                                               const float* __restrict__ W,
                                               u16* __restrict__ out,
                                               const float* __restrict__ cosT,
                                               const float* __restrict__ sinT,
                                               const int N, const int K) {
  __shared__ u16 Ah[64][32], Al[64][32];
  __shared__ u16 Bh[64][32], Bl[64][32];  // [n][k]
  const int tid = threadIdx.x;
  const int wave = tid >> 6, lane = tid & 63;
  const int m0 = blockIdx.y << 6, n0 = blockIdx.x << 6;
  const f32x4 zero = {0.f, 0.f, 0.f, 0.f};
  f32x4 acc[4] = {zero, zero, zero, zero};
  const int srow = tid >> 2, koff = ((tid & 3) << 3) ^ swz(tid >> 2);
  const int lrow = lane & 15, lk = ((lane >> 4) << 3) ^ swz(lane & 15);
  for (int kk = 0; kk < K; kk += 32) {
    const int kg = (tid & 3) << 3;  // global k sub-offset (unswizzled)
    float av[8];
    *(float4*)(av) = *(const float4*)(&A[(size_t)(m0 + srow) * K + kk + kg]);
    *(float4*)(av + 4) =
        *(const float4*)(&A[(size_t)(m0 + srow) * K + kk + kg + 4]);
    uint4 hi, lo;
    split8(av, hi, lo);
    *(uint4*)(&Ah[srow][koff]) = hi;
    *(uint4*)(&Al[srow][koff]) = lo;
    float wv[8];
#pragma unroll
    for (int j = 0; j < 8; ++j)
      wv[j] = W[(size_t)(kk + kg + j) * N + n0 + srow];
    split8(wv, hi, lo);
    *(uint4*)(&Bh[srow][koff]) = hi;
    *(uint4*)(&Bl[srow][koff]) = lo;
    __syncthreads();
    short8 ah = *(const short8*)(&Ah[(wave << 4) + lrow][lk]);
    short8 al = *(const short8*)(&Al[(wave << 4) + lrow][lk]);
#pragma unroll
    for (int ns = 0; ns < 4; ++ns) {
      short8 bh = *(const short8*)(&Bh[(ns << 4) + lrow][lk]);
      short8 bl = *(const short8*)(&Bl[(ns << 4) + lrow][lk]);
      acc[ns] = mfma16x16x32(ah, bh, acc[ns]);
      acc[ns] = mfma16x16x32(al, bh, acc[ns]);
      acc[ns] = mfma16x16x32(ah, bl, acc[ns]);
    }
    __syncthreads();
  }
  const int r0 = m0 + (wave << 4) + ((lane >> 4) << 2);
  const int cb = n0 + (lane & 15);
#pragma unroll
  for (int ns = 0; ns < 4; ++ns) {
#pragma unroll
    for (int r = 0; r < 4; ++r) {
      const int rg = r0 + r;
      const int cg = cb + (ns << 4);
      float v = acc[ns][r];
      float pv = __shfl_xor(v, 1);  // partner column of the RoPE pair
      const int t = rg & (T_ - 1);
      const int c = (MODE == 1) ? (cg & (C_ - 1)) : cg;
      const int i = c >> 1;
      const float cf = cosT[(t << 8) + i];
      const float sf = sinT[(t << 8) + i];
      float x1 = (lane & 1) ? pv : v;
      float x2 = (lane & 1) ? v : pv;
      float y = (lane & 1) ? (x1 * sf + x2 * cf) : (x1 * cf - x2 * sf);
      if (MODE == 1) y *= 0.044194173824159216f;  // 1/sqrt(512)
      const u16 hi = f2bf(y);
      const u16 lo = f2bf(y - bf2f(hi));
      size_t rowoff;
      if (MODE == 1) {
        const int b = rg >> 11, n = cg >> 9;
        rowoff = ((size_t)((b * NB_ + n) * T_ + t)) * C2_;
      } else {
        rowoff = (size_t)rg * C2_;
      }
      out[rowoff + c] = hi;
      out[rowoff + C_ + c] = lo;
    }
  }
}

// ---------------------------------------------------------------------------
// Plain hi-only GEMM: A f32 (AF32=1) or bf16, W f32; out bf16 or f32 (OF32).
// ---------------------------------------------------------------------------
template <int AF32, int OF32>
__global__ __launch_bounds__(256) void gemm_hi(const void* __restrict__ Ap,
                                               const float* __restrict__ W,
                                               void* __restrict__ outp,
                                               const int N, const int K) {
  __shared__ u16 As[64][32];
  __shared__ u16 Bs[64][32];
  const int tid = threadIdx.x;
  const int wave = tid >> 6, lane = tid & 63;
  const int m0 = blockIdx.y << 6, n0 = blockIdx.x << 6;
  const f32x4 zero = {0.f, 0.f, 0.f, 0.f};
  f32x4 acc[4] = {zero, zero, zero, zero};
  const int srow = tid >> 2, koff = ((tid & 3) << 3) ^ swz(tid >> 2);
  const int lrow = lane & 15, lk = ((lane >> 4) << 3) ^ swz(lane & 15);
  for (int kk = 0; kk < K; kk += 32) {
    const int kg = (tid & 3) << 3;
    if (AF32) {
      const float* A = (const float*)Ap;
      float av[8];
      *(float4*)(av) = *(const float4*)(&A[(size_t)(m0 + srow) * K + kk + kg]);
      *(float4*)(av + 4) =
          *(const float4*)(&A[(size_t)(m0 + srow) * K + kk + kg + 4]);
      uint4 hi;
      hi.x = f2bf(av[0]) | ((unsigned)f2bf(av[1]) << 16);
      hi.y = f2bf(av[2]) | ((unsigned)f2bf(av[3]) << 16);
      hi.z = f2bf(av[4]) | ((unsigned)f2bf(av[5]) << 16);
      hi.w = f2bf(av[6]) | ((unsigned)f2bf(av[7]) << 16);
      *(uint4*)(&As[srow][koff]) = hi;
    } else {
      const u16* A = (const u16*)Ap;
      *(uint4*)(&As[srow][koff]) =
          *(const uint4*)(&A[(size_t)(m0 + srow) * K + kk + kg]);
    }
    uint4 hi;
    {
      float w[8];
#pragma unroll
      for (int j = 0; j < 8; ++j)
        w[j] = W[(size_t)(kk + kg + j) * N + n0 + srow];
      hi.x = f2bf(w[0]) | ((unsigned)f2bf(w[1]) << 16);
      hi.y = f2bf(w[2]) | ((unsigned)f2bf(w[3]) << 16);
      hi.z = f2bf(w[4]) | ((unsigned)f2bf(w[5]) << 16);
      hi.w = f2bf(w[6]) | ((unsigned)f2bf(w[7]) << 16);
    }
    *(uint4*)(&Bs[srow][koff]) = hi;
    __syncthreads();
    short8 af = *(const short8*)(&As[(wave << 4) + lrow][lk]);
#pragma unroll
    for (int ns = 0; ns < 4; ++ns) {
      short8 bf = *(const short8*)(&Bs[(ns << 4) + lrow][lk]);
      acc[ns] = mfma16x16x32(af, bf, acc[ns]);
    }
    __syncthreads();
  }
  const int r0 = m0 + (wave << 4) + ((lane >> 4) << 2);
  const int cb = n0 + (lane & 15);
#pragma unroll
  for (int ns = 0; ns < 4; ++ns) {
#pragma unroll
    for (int r = 0; r < 4; ++r) {
      const size_t idx = (size_t)(r0 + r) * N + cb + (ns << 4);
      if (OF32) ((float*)outp)[idx] = acc[ns][r];
      else ((u16*)outp)[idx] = f2bf(acc[ns][r]);
    }
  }
}

// ---------------------------------------------------------------------------
// Vraw (B,T,NB*C) bf16 -> VT (B,NB,C,T) tiled transpose, 64x64 tiles.
// ---------------------------------------------------------------------------
__global__ __launch_bounds__(256) void transpose_v_k(const u16* __restrict__ Vraw,
                                                     u16* __restrict__ VT) {
  const int bid = blockIdx.x;
  const int ct = bid & 7;
  const int ttile = (bid >> 3) & 31;
  const int n = (bid >> 8) & 3;
  const int b = bid >> 10;
  __shared__ u16 tile[64][68];
  const int tid = threadIdx.x;
  const int rr = tid >> 4;
  const int cc = (tid & 15) << 2;
  const int t0 = ttile << 6, c0 = ct << 6;
#pragma unroll
  for (int it = 0; it < 4; ++it) {
    const int r = (it << 4) + rr;
    *(ushort4*)(&tile[r][cc]) = *(const ushort4*)(
        &Vraw[((size_t)((b << 11) + t0 + r)) * (NB_ * C_) + n * C_ + c0 + cc]);
  }
  __syncthreads();
#pragma unroll
  for (int it = 0; it < 4; ++it) {
    const int c = (it << 4) + rr;
    ushort4 w;
    w.x = tile[cc + 0][c]; w.y = tile[cc + 1][c];
    w.z = tile[cc + 2][c]; w.w = tile[cc + 3][c];
    *(ushort4*)(&VT[((size_t)((b * NB_ + n) * C_ + c0 + c)) * T_ + t0 + cc]) = w;
  }
}

// ---------------------------------------------------------------------------
// Scores (R18 form): per lower-tri 64x64 (t,s) tile, 4 branches, fused split
// segments (40KB LDS), swizzled LDS, XCD-chunked tri swizzle.
// ---------------------------------------------------------------------------
__global__ __launch_bounds__(256) void scores_k(const u16* __restrict__ Qcat,
                                                const u16* __restrict__ Kcat,
                                                u16* __restrict__ Mout,
                                                u8* __restrict__ Mask) {
  // XCD-chunked swizzle: 8 XCDs x 66 consecutive tris each (bijective).
  const int tri = ((blockIdx.x & 7) * 66) + (blockIdx.x >> 3);
  int tt = (int)((sqrtf(8.f * (float)tri + 1.f) - 1.f) * 0.5f);
  while ((tt + 1) * (tt + 2) / 2 <= tri) ++tt;
  while (tt * (tt + 1) / 2 > tri) --tt;
  const int ss = tri - tt * (tt + 1) / 2;
  const int b = blockIdx.y;
  __shared__ u16 Qh[NB_][64][32], Ql[NB_][64][32];
  __shared__ u16 Kh[64][32], Kl[64][32];
  const int tid = threadIdx.x;
  const int wave = tid >> 6, lane = tid & 63;
  const int t0 = tt << 6, s0 = ss << 6;
  const f32x4 zero = {0.f, 0.f, 0.f, 0.f};
  f32x4 acc[NB_][4];
  for (int n = 0; n < NB_; ++n)
    for (int j = 0; j < 4; ++j) acc[n][j] = zero;
  const int srow = tid >> 2, koff = ((tid & 3) << 3) ^ swz(tid >> 2);
  const int lrow = lane & 15, lk = ((lane >> 4) << 3) ^ swz(lane & 15);
  const int kg = (tid & 3) << 3;
  for (int kk = 0; kk < C_; kk += 32) {
#pragma unroll
    for (int n = 0; n < NB_; ++n) {
      const size_t qb =
          ((size_t)((b * NB_ + n) * T_ + t0 + srow)) * C2_ + kk + kg;
      *(uint4*)(&Qh[n][srow][koff]) = *(const uint4*)(&Qcat[qb]);
      *(uint4*)(&Ql[n][srow][koff]) = *(const uint4*)(&Qcat[qb + C_]);
    }
    const size_t kb = ((size_t)((b << 11) + s0 + srow)) * C2_ + kk + kg;
    *(uint4*)(&Kh[srow][koff]) = *(const uint4*)(&Kcat[kb]);
    *(uint4*)(&Kl[srow][koff]) = *(const uint4*)(&Kcat[kb + C_]);
    __syncthreads();
    short8 qh[NB_], ql[NB_];
#pragma unroll
    for (int n = 0; n < NB_; ++n) {
      qh[n] = *(const short8*)(&Qh[n][(wave << 4) + lrow][lk]);
      ql[n] = *(const short8*)(&Ql[n][(wave << 4) + lrow][lk]);
    }
#pragma unroll
    for (int ns = 0; ns < 4; ++ns) {
      short8 kh = *(const short8*)(&Kh[(ns << 4) + lrow][lk]);
      short8 kl = *(const short8*)(&Kl[(ns << 4) + lrow][lk]);
#pragma unroll
      for (int n = 0; n < NB_; ++n) {
        acc[n][ns] = mfma16x16x32(qh[n], kh, acc[n][ns]);
        acc[n][ns] = mfma16x16x32(ql[n], kh, acc[n][ns]);
        acc[n][ns] = mfma16x16x32(qh[n], kl, acc[n][ns]);
      }
    }
    __syncthreads();
  }
  const int tb = t0 + (wave << 4) + ((lane >> 4) << 2);
  const int sb = s0 + (lane & 15);
#pragma unroll
  for (int ns = 0; ns < 4; ++ns) {
#pragma unroll
    for (int r = 0; r < 4; ++r) {
      const int t = tb + r, s = sb + (ns << 4);
      float a0 = acc[0][ns][r], a1 = acc[1][ns][r];
      float a2 = acc[2][ns][r], a3 = acc[3][ns][r];
      float m = fmaxf(fmaxf(a0, a1), fmaxf(a2, a3));
      u8 msk = (u8)((a0 == m) | ((a1 == m) << 1) | ((a2 == m) << 2) |
                    ((a3 == m) << 3));
      if (s > t) { m = -__builtin_inff(); msk = 0; }
      const size_t idx = (size_t)b * T_ * T_ + (size_t)t * T_ + s;
      Mout[idx] = f2bf(m);
      Mask[idx] = msk;
    }
  }
}

// ---------------------------------------------------------------------------
// Per-row softmax stats from bf16 M: rowmax, 1/sum(exp). One wave per (b,t).
// ---------------------------------------------------------------------------
__global__ __launch_bounds__(256) void rowstats_k(const u16* __restrict__ Mb,
                                                  float* __restrict__ Rm,
                                                  float* __restrict__ Rz) {
  const int r = (blockIdx.x << 2) + (threadIdx.x >> 6);
  const int lane = threadIdx.x & 63;
  const int b = r >> 11, t = r & (T_ - 1);
  const u16* row = Mb + (size_t)b * T_ * T_ + (size_t)t * T_;
  float m = -__builtin_inff();
  for (int s = lane; s <= t; s += 64) m = fmaxf(m, bf2f(row[s]));
#pragma unroll
  for (int off = 32; off; off >>= 1) m = fmaxf(m, __shfl_xor(m, off));
  float z = 0.f;
  for (int s = lane; s <= t; s += 64) z += __expf(bf2f(row[s]) - m);
#pragma unroll
  for (int off = 32; off; off >>= 1) z += __shfl_xor(z, off);
  if (lane == 0) { Rm[r] = m; Rz[r] = 1.f / z; }
}

// ---------------------------------------------------------------------------
// Routed PV, R20: 512-thread blocks, 64-wide c stripe, grid (16,8,2).
// Fused P-build (P = f2bf(__expf(M-rm)*rz)) at staging; staging shared by
// 8 waves -> replication 16->8 vs R19. Paired tiles (x and 31-x, 66 chunks).
// Wave (wq=wave&3, ch=wave>>2) computes 16t x 32c. LDS 32KB, one-chunk
// register prefetch, uniform col^swz(row) LDS swizzle.
// ---------------------------------------------------------------------------
__global__ __launch_bounds__(512) void pv_k(const u16* __restrict__ Mb,
                                            const float* __restrict__ Rm,
                                            const float* __restrict__ Rz,
                                            const u8* __restrict__ Mask,
                                            const u16* __restrict__ VT,
                                            u16* __restrict__ Y) {
  const int ypair = blockIdx.x, cblk = blockIdx.y, b = blockIdx.z;
  const int c0 = cblk << 6;  // 64-wide c stripe
  __shared__ u16 Ps[NB_][64][32];
  __shared__ u16 Vs[NB_][64][32];
  const int tid = threadIdx.x;
  const int wave = tid >> 6, lane = tid & 63;
  const int wq = wave & 3, ch = wave >> 2;            // t-quarter, c-half
  const int row8 = tid >> 3, off4 = (tid & 7) << 2;   // 64 rows x uint2
  const int scol = off4 ^ swz(row8);                  // swizzled LDS col
  const int lrow = lane & 15, lk = ((lane >> 4) << 3) ^ swz(lane & 15);
  const f32x4 zero = {0.f, 0.f, 0.f, 0.f};
  const size_t vrow_base[NB_] = {
      ((size_t)((b * NB_ + 0) * C_ + c0 + row8)) * T_,
      ((size_t)((b * NB_ + 1) * C_ + c0 + row8)) * T_,
      ((size_t)((b * NB_ + 2) * C_ + c0 + row8)) * T_,
      ((size_t)((b * NB_ + 3) * C_ + c0 + row8)) * T_};

  for (int half = 0; half < 2; ++half) {
    const int tt = half ? (31 - ypair) : ypair;
    const int t0 = tt << 6;
    const int nchunk = (tt + 1) << 1;
    const int rg = (b << 11) + t0 + row8;       // this thread's (b,t) row
    const size_t pro = (size_t)rg << 11;
    const float rm = Rm[rg], rz = Rz[rg];       // per-row scalars, once/half
    f32x4 acc[2] = {zero, zero};
    uint2 pu; unsigned mk1; uint2 vv[NB_];
    // prefetch chunk 0 (M values; converted to P at staging)
    pu = *(const uint2*)(&Mb[pro + off4]);
    mk1 = *(const unsigned*)(&Mask[pro + off4]);
#pragma unroll
    for (int n = 0; n < NB_; ++n)
      vv[n] = *(const uint2*)(&VT[vrow_base[n] + off4]);
    for (int ck = 0; ck < nchunk; ++ck) {
      u16 m4[4] = {(u16)pu.x, (u16)(pu.x >> 16), (u16)pu.y, (u16)(pu.y >> 16)};
      u16 p[4];
#pragma unroll
      for (int j = 0; j < 4; ++j)
        p[j] = f2bf(__expf(bf2f(m4[j]) - rm) * rz);  // v_exp_f32 fast path
      u8 mk[4] = {(u8)mk1, (u8)(mk1 >> 8), (u8)(mk1 >> 16), (u8)(mk1 >> 24)};
#pragma unroll
      for (int n = 0; n < NB_; ++n) {
        uint2 wv;
        wv.x = (unsigned)(((mk[0] >> n) & 1) ? p[0] : 0) |
               ((unsigned)(((mk[1] >> n) & 1) ? p[1] : 0) << 16);
        wv.y = (unsigned)(((mk[2] >> n) & 1) ? p[2] : 0) |
               ((unsigned)(((mk[3] >> n) & 1) ? p[3] : 0) << 16);
        *(uint2*)(&Ps[n][row8][scol]) = wv;
        *(uint2*)(&Vs[n][row8][scol]) = vv[n];
      }
      __syncthreads();
      if (ck + 1 < nchunk) {  // prefetch next chunk (overlaps MFMA)
        const int sB = (ck + 1) << 5;
        pu = *(const uint2*)(&Mb[pro + sB + off4]);
        mk1 = *(const unsigned*)(&Mask[pro + sB + off4]);
#pragma unroll
        for (int n = 0; n < NB_; ++n)
          vv[n] = *(const uint2*)(&VT[vrow_base[n] + sB + off4]);
      }
#pragma unroll
      for (int n = 0; n < NB_; ++n) {
        short8 af = *(const short8*)(&Ps[n][(wq << 4) + lrow][lk]);
#pragma unroll
        for (int cs = 0; cs < 2; ++cs) {
          short8 bf =
              *(const short8*)(&Vs[n][(ch << 5) + (cs << 4) + lrow][lk]);
          acc[cs] = mfma16x16x32(af, bf, acc[cs]);
        }
      }
      __syncthreads();
    }
    const int tb = t0 + (wq << 4) + ((lane >> 4) << 2);
    const int cbs = c0 + (ch << 5) + (lane & 15);
#pragma unroll
    for (int cs = 0; cs < 2; ++cs) {
#pragma unroll
      for (int r = 0; r < 4; ++r) {
        Y[(size_t)((b << 11) + tb + r) * C_ + cbs + (cs << 4)] =
            f2bf(acc[cs][r]);
      }
    }
  }
}

// ---------------------------------------------------------------------------
extern "C" void kernel_launch(void* const* d_in, const int* in_sizes, int n_in,
                              void* d_out, int out_size, void* d_ws,
                              size_t ws_size, hipStream_t stream) {
  (void)in_sizes; (void)n_in; (void)out_size; (void)ws_size;
  const float* a    = (const float*)d_in[0];
  const float* x    = (const float*)d_in[1];
  const float* Wq   = (const float*)d_in[2];
  const float* Wk   = (const float*)d_in[3];
  const float* Wv   = (const float*)d_in[4];
  const float* Wo   = (const float*)d_in[5];
  const float* cosT = (const float*)d_in[6];
  const float* sinT = (const float*)d_in[7];

  char* w = (char*)d_ws;
  u16* Qcat   = (u16*)(w + 0);           // 33.5MB -> first 4.2MB reused as Y
  u16* Kcat   = (u16*)(w + 33554432);    //  8.4MB
  u16* Vraw   = (u16*)(w + 41943040);    // 16.8MB -> reused as bf16 M
  u16* VT     = (u16*)(w + 58720256);    // 16.8MB
  u8*  Mask   = (u8*)(w + 75497472);     //  8.4MB
  float* Rm   = (float*)(w + 83886080);  //  16KB
  float* Rz   = (float*)(w + 83902464);  //  16KB
  u16* Mb     = Vraw;
  u16* Y      = Qcat;

  const dim3 blk(256);
  gemm_qk<1><<<dim3(32, 64), blk, 0, stream>>>(a, Wq, Qcat, cosT, sinT, 2048, 512);
  gemm_qk<2><<<dim3(8, 64), blk, 0, stream>>>(x, Wk, Kcat, cosT, sinT, 512, 512);
  gemm_hi<1, 0><<<dim3(32, 64), blk, 0, stream>>>(a, Wv, (void*)Vraw, 2048, 512);
  transpose_v_k<<<dim3(2048), blk, 0, stream>>>(Vraw, VT);
  scores_k<<<dim3(528, 2), blk, 0, stream>>>(Qcat, Kcat, Mb, Mask);
  rowstats_k<<<dim3(1024), blk, 0, stream>>>(Mb, Rm, Rz);
  pv_k<<<dim3(16, 8, 2), dim3(512), 0, stream>>>(Mb, Rm, Rz, Mask, VT, Y);
  gemm_hi<0, 1><<<dim3(8, 64), blk, 0, stream>>>(Y, Wo, d_out, 512, 512);
}